// Round 1
// baseline (1117.806 us; speedup 1.0000x reference)
//
#include <hip/hip_runtime.h>
#include <stdint.h>

typedef unsigned int u32;
typedef unsigned long long u64;

// ---------------- problem constants ----------------
#define BATCH 4
#define NSEQ  8192
#define DIM   64
#define NH    8
#define CSZ   128   // cluster size (Q_ATTN == K_ATTN)
#define NCLU  64    // clusters per (h,b)

// JAX threefry bit-derivation scheme for alpha/beta:
//  0 = legacy threefry_random_bits (halved-counter)
//  1 = partitionable, bits = x0^x1   <-- shipped guess (modern JAX default flag)
//  2 = partitionable, bits = x0 (hi word)
//  3 = partitionable, bits = x1 (lo word)
#define RNG_SCHEME 1

// ---------------- workspace layout ----------------
// float-index offsets unless noted _B (bytes)
#define WS_ALPHA   0          // alpha[8][66] f32 (528)
#define WS_BETA    528        // beta[8] f32
#define WS_MAXB    536        // maxnorm bits [2][4] u32
#define WS_QN      1024       // qn[2][4][8192] f32  (65536)
#define WS_KEYS_B  266240     // keys[2][8][4][8192] u32 (2 MiB), sorted in place
#define WS_LSE_B   2363392    // lse[8][4][8192] f32 (1 MiB)
#define WS_BO_B    3411968    // bo[8][4][8192][64] f32 (64 MiB)
// total = 70,520,832 bytes

// ---------------- Threefry-2x32 (JAX) ----------------
__device__ __forceinline__ void tf2x32(u32 k0, u32 k1, u32 x0, u32 x1, u32& o0, u32& o1) {
  u32 ks2 = k0 ^ k1 ^ 0x1BD11BDAu;
  x0 += k0; x1 += k1;
#define TF_RND(r) { x0 += x1; x1 = (x1 << (r)) | (x1 >> (32 - (r))); x1 ^= x0; }
  TF_RND(13) TF_RND(15) TF_RND(26) TF_RND(6)
  x0 += k1; x1 += ks2 + 1u;
  TF_RND(17) TF_RND(29) TF_RND(16) TF_RND(24)
  x0 += ks2; x1 += k0 + 2u;
  TF_RND(13) TF_RND(15) TF_RND(26) TF_RND(6)
  x0 += k0; x1 += k1 + 3u;
  TF_RND(17) TF_RND(29) TF_RND(16) TF_RND(24)
  x0 += k1; x1 += ks2 + 4u;
  TF_RND(13) TF_RND(15) TF_RND(26) TF_RND(6)
  x0 += ks2; x1 += k0 + 5u;
#undef TF_RND
  o0 = x0; o1 = x1;
}

// JAX uniform [0,1): bitcast((bits>>9)|0x3f800000) - 1.0  (exact subtraction)
__device__ __forceinline__ float bits01(u32 b) {
  return __uint_as_float((b >> 9) | 0x3f800000u) - 1.0f;
}

// XLA ErfInv32 (Giles polynomial), exact fp32 op sequence (no FMA contraction).
__device__ __forceinline__ float xla_erfinv(float x) {
  float x2 = __fmul_rn(x, x);
  float w = (float)(-log1p(-(double)x2));   // log1p in f64, round once (<=1ulp vs XLA)
  float p;
  if (w < 5.0f) {
    float ww = __fsub_rn(w, 2.5f);
    p = 2.81022636e-08f;
    p = __fadd_rn(3.43273939e-07f, __fmul_rn(p, ww));
    p = __fadd_rn(-3.5233877e-06f, __fmul_rn(p, ww));
    p = __fadd_rn(-4.39150654e-06f, __fmul_rn(p, ww));
    p = __fadd_rn(0.00021858087f, __fmul_rn(p, ww));
    p = __fadd_rn(-0.00125372503f, __fmul_rn(p, ww));
    p = __fadd_rn(-0.00417768164f, __fmul_rn(p, ww));
    p = __fadd_rn(0.246640727f, __fmul_rn(p, ww));
    p = __fadd_rn(1.50140941f, __fmul_rn(p, ww));
  } else {
    float ww = __fsub_rn(__fsqrt_rn(w), 3.0f);
    p = -0.000200214257f;
    p = __fadd_rn(0.000100950558f, __fmul_rn(p, ww));
    p = __fadd_rn(0.00134934322f, __fmul_rn(p, ww));
    p = __fadd_rn(-0.00367342844f, __fmul_rn(p, ww));
    p = __fadd_rn(0.00573950773f, __fmul_rn(p, ww));
    p = __fadd_rn(-0.0076224613f, __fmul_rn(p, ww));
    p = __fadd_rn(0.00943887047f, __fmul_rn(p, ww));
    p = __fadd_rn(1.00167406f, __fmul_rn(p, ww));
    p = __fadd_rn(2.83297682f, __fmul_rn(p, ww));
  }
  return __fmul_rn(p, x);
}

// ---------------- k_rng: alpha/beta constants + zero max-norm slots ----------------
__global__ __launch_bounds__(256) void smyrf_rng(float* ws) {
  int t = threadIdx.x;
  float* alpha = ws + WS_ALPHA;
  float* beta  = ws + WS_BETA;
  u32*   maxb  = (u32*)(ws + WS_MAXB);
  if (t < 8) maxb[t] = 0u;                 // d_ws is poisoned each call
  u32 ka0, ka1, kb0, kb1;
  tf2x32(0u, 42u, 0u, 0u, ka0, ka1);       // fold_in(key(42), 0)
  tf2x32(0u, 42u, 0u, 1u, kb0, kb1);       // fold_in(key(42), 1)
  const float LO = __uint_as_float(0xBF7FFFFFu);   // nextafter(-1,0)
  const float SQ2 = 1.4142135623730951f;           // rounds to fp32 sqrt(2)
#if RNG_SCHEME == 0
  for (int i = t; i < 264; i += 256) {
    u32 o0, o1; tf2x32(ka0, ka1, (u32)i, (u32)(i + 264), o0, o1);
    float u0 = __fadd_rn(__fmul_rn(bits01(o0), 2.0f), LO);
    float u1 = __fadd_rn(__fmul_rn(bits01(o1), 2.0f), LO);
    alpha[i]       = __fmul_rn(SQ2, xla_erfinv(u0));
    alpha[i + 264] = __fmul_rn(SQ2, xla_erfinv(u1));
  }
  if (t < 4) {
    u32 o0, o1; tf2x32(kb0, kb1, (u32)t, (u32)(t + 4), o0, o1);
    beta[t]     = bits01(o0);
    beta[t + 4] = bits01(o1);
  }
#else
  for (int i = t; i < 528; i += 256) {
    u32 o0, o1; tf2x32(ka0, ka1, 0u, (u32)i, o0, o1);
#if RNG_SCHEME == 1
    u32 bits = o0 ^ o1;
#elif RNG_SCHEME == 2
    u32 bits = o0;
#else
    u32 bits = o1;
#endif
    float u = __fadd_rn(__fmul_rn(bits01(bits), 2.0f), LO);
    alpha[i] = __fmul_rn(SQ2, xla_erfinv(u));
  }
  if (t < 8) {
    u32 o0, o1; tf2x32(kb0, kb1, 0u, (u32)t, o0, o1);
#if RNG_SCHEME == 1
    beta[t] = bits01(o0 ^ o1);
#elif RNG_SCHEME == 2
    beta[t] = bits01(o0);
#else
    beta[t] = bits01(o1);
#endif
  }
#endif
}

// ---------------- k_norms: per-token ||x||, per-batch max via atomicMax on bits ----------------
__global__ __launch_bounds__(256) void smyrf_norms(const float* __restrict__ Q,
                                                   const float* __restrict__ Kk,
                                                   float* ws) {
  int tid = blockIdx.x * 256 + threadIdx.x;        // 65536 = 2*4*8192
  int tensor = tid >> 15;
  const float* x = (tensor ? Kk : Q) + (size_t)(tid & 32767) * DIM;
  const float4* x4 = (const float4*)x;
  double s = 0.0;
  #pragma unroll
  for (int i = 0; i < 16; ++i) {
    float4 v = x4[i];
    s += (double)v.x * v.x + (double)v.y * v.y + (double)v.z * v.z + (double)v.w * v.w;
  }
  float qn = (float)sqrt(s);
  (ws + WS_QN)[tid] = qn;
  int b = (tid >> 13) & 3;
  atomicMax((u32*)(ws + WS_MAXB) + tensor * 4 + b, __float_as_uint(qn));
}

// ---------------- k_keys: E2LSH bucket -> stable-sort key (bucket<<13 | idx) ----------------
__global__ __launch_bounds__(256) void smyrf_keys(const float* __restrict__ Q,
                                                  const float* __restrict__ Kk,
                                                  float* ws) {
  int tid = blockIdx.x * 256 + threadIdx.x;        // 65536
  int tensor = tid >> 15;
  int b = (tid >> 13) & 3;
  int n = tid & 8191;
  const float* x = (tensor ? Kk : Q) + (size_t)(tid & 32767) * DIM;
  float r[64];
  const float4* x4 = (const float4*)x;
  #pragma unroll
  for (int i = 0; i < 16; ++i) {
    float4 v = x4[i];
    r[4 * i] = v.x; r[4 * i + 1] = v.y; r[4 * i + 2] = v.z; r[4 * i + 3] = v.w;
  }
  const float* alpha = ws + WS_ALPHA;
  const float* beta  = ws + WS_BETA;
  const u32*   maxb  = (const u32*)(ws + WS_MAXB);
  float qn = (ws + WS_QN)[tid];
  float mq = __uint_as_float(maxb[b]);
  float mk = __uint_as_float(maxb[4 + b]);
  float M2 = __fadd_rn(__fmul_rn(mq, mq), __fmul_rn(mk, mk));   // max_qn^2 + max_kn^2 (fp32)
  float ex = __fsqrt_rn(fmaxf(__fsub_rn(M2, __fmul_rn(qn, qn)), 0.0f));
  u32* keys = (u32*)((char*)ws + WS_KEYS_B);
  #pragma unroll 1
  for (int hh = 0; hh < NH; ++hh) {
    const float* al = alpha + hh * 66;
    double dot = 0.0;
    #pragma unroll
    for (int d = 0; d < 64; ++d) dot = fma((double)r[d], (double)al[d], dot);
    dot = fma((double)ex, (double)al[64 + tensor], dot);        // augmented coord (q:64, k:65)
    float val = __fadd_rn((float)dot, beta[hh]);                // fp32 round then +beta, /1.0
    float fb = floorf(val);
    int ib = (fb >= 262143.f) ? 262143 : ((fb <= -262144.f) ? -262144 : (int)fb);
    keys[((size_t)tensor * NH * BATCH + (size_t)hh * BATCH + b) * NSEQ + n] =
        ((u32)(ib + 262144) << 13) | (u32)n;                    // stable: idx in low 13 bits
  }
}

// ---------------- k_sort: in-LDS bitonic, one (tensor,h,b) segment per block ----------------
__global__ __launch_bounds__(1024) void smyrf_sort(float* ws) {
  __shared__ u32 arr[8192];
  u32* base = (u32*)((char*)ws + WS_KEYS_B) + (size_t)blockIdx.x * 8192;
  int t = threadIdx.x;
  for (int i = t; i < 8192; i += 1024) arr[i] = base[i];
  __syncthreads();
  for (int kk = 2; kk <= 8192; kk <<= 1) {
    for (int j = kk >> 1; j > 0; j >>= 1) {
      for (int i = t; i < 8192; i += 1024) {
        int ixj = i ^ j;
        if (ixj > i) {
          u32 A = arr[i], B = arr[ixj];
          bool up = (i & kk) == 0;
          if ((A > B) == up) { arr[i] = B; arr[ixj] = A; }
        }
      }
      __syncthreads();
    }
  }
  for (int i = t; i < 8192; i += 1024) base[i] = arr[i];
}

// ---------------- k_attn: per-cluster softmax attention (fp32 VALU), scatter to orig order ----
// block = 256 threads, one (h,b,c) cluster. 8x8 register tiles; P staged through LDS in 2 halves.
__global__ __launch_bounds__(256, 2) void smyrf_attn(const float* __restrict__ Q,
                                                     const float* __restrict__ K,
                                                     const float* __restrict__ V,
                                                     float* __restrict__ ws) {
  __shared__ float smA[64 * 128];  // Q^T [d][r]; later V half-tile [64][64] in first 4096
  __shared__ float smB[64 * 128];  // K^T [d][c]; later P half [cc_local][r]
  int id = blockIdx.x;
  int c = id & 63, b = (id >> 6) & 3, h = id >> 8;
  int t = threadIdx.x;

  const u32* keys = (const u32*)((const char*)ws + WS_KEYS_B);
  const u32* qk = keys + ((size_t)h * BATCH + b) * NSEQ + c * CSZ;
  const u32* kk = keys + (size_t)NH * BATCH * NSEQ + ((size_t)h * BATCH + b) * NSEQ + c * CSZ;
  const float* Qb = Q + (size_t)b * NSEQ * DIM;
  const float* Kb = K + (size_t)b * NSEQ * DIM;
  const float* Vb = V + (size_t)b * NSEQ * DIM;

  // stage Q^T / K^T: row = i&127 -> conflict-free LDS writes (bank = row%32, 2 lanes each)
  for (int i = t; i < 2048; i += 256) {
    int row = i & 127, c4 = i >> 7;
    int oq = (int)(qk[row] & 8191);
    float4 f = *(const float4*)(Qb + (size_t)oq * DIM + c4 * 4);
    smA[(c4 * 4 + 0) * 128 + row] = f.x;
    smA[(c4 * 4 + 1) * 128 + row] = f.y;
    smA[(c4 * 4 + 2) * 128 + row] = f.z;
    smA[(c4 * 4 + 3) * 128 + row] = f.w;
    int ok = (int)(kk[row] & 8191);
    float4 g = *(const float4*)(Kb + (size_t)ok * DIM + c4 * 4);
    smB[(c4 * 4 + 0) * 128 + row] = g.x;
    smB[(c4 * 4 + 1) * 128 + row] = g.y;
    smB[(c4 * 4 + 2) * 128 + row] = g.z;
    smB[(c4 * 4 + 3) * 128 + row] = g.w;
  }
  __syncthreads();

  // scores: thread (rt,ct) owns rows rt*8.., cols ct*8..
  int rt = t >> 4, ct = t & 15;
  float s[8][8];
  #pragma unroll
  for (int j = 0; j < 8; ++j)
    #pragma unroll
    for (int l = 0; l < 8; ++l) s[j][l] = 0.0f;
  #pragma unroll 2
  for (int d = 0; d < 64; ++d) {
    float4 qa = *(const float4*)&smA[d * 128 + rt * 8];
    float4 qb4 = *(const float4*)&smA[d * 128 + rt * 8 + 4];
    float4 ka = *(const float4*)&smB[d * 128 + ct * 8];
    float4 kb4 = *(const float4*)&smB[d * 128 + ct * 8 + 4];
    float qv[8] = {qa.x, qa.y, qa.z, qa.w, qb4.x, qb4.y, qb4.z, qb4.w};
    float kv[8] = {ka.x, ka.y, ka.z, ka.w, kb4.x, kb4.y, kb4.z, kb4.w};
    #pragma unroll
    for (int j = 0; j < 8; ++j)
      #pragma unroll
      for (int l = 0; l < 8; ++l) s[j][l] = fmaf(qv[j], kv[l], s[j][l]);
  }

  // online-free softmax (full row present across the 16-lane ct group)
  float inv8[8];
  float* lse = (float*)((char*)ws + WS_LSE_B);
  #pragma unroll
  for (int j = 0; j < 8; ++j) {
    float m = s[j][0];
    #pragma unroll
    for (int l = 1; l < 8; ++l) m = fmaxf(m, s[j][l]);
    m = fmaxf(m, __shfl_xor(m, 1));
    m = fmaxf(m, __shfl_xor(m, 2));
    m = fmaxf(m, __shfl_xor(m, 4));
    m = fmaxf(m, __shfl_xor(m, 8));
    float sum = 0.0f;
    #pragma unroll
    for (int l = 0; l < 8; ++l) { s[j][l] = __expf(s[j][l] - m); sum += s[j][l]; }
    sum += __shfl_xor(sum, 1);
    sum += __shfl_xor(sum, 2);
    sum += __shfl_xor(sum, 4);
    sum += __shfl_xor(sum, 8);
    inv8[j] = 1.0f / sum;
    if (ct == 0) {
      int oq = (int)(qk[rt * 8 + j] & 8191);
      lse[(((size_t)h * BATCH + b) << 13) + oq] = m + __logf(sum);
    }
  }

  // PV in two cc-halves: P^T half in smB [64][128], V half in smA [64][64]
  float acc[8][8];
  #pragma unroll
  for (int j = 0; j < 8; ++j)
    #pragma unroll
    for (int l = 0; l < 8; ++l) acc[j][l] = 0.0f;
  int par = (t >> 3) & 1;   // cc parity; partner = t^8
  int ct8 = t & 7;          // dv tile (8 wide)
  #pragma unroll 1
  for (int pass = 0; pass < 2; ++pass) {
    __syncthreads();   // prior readers of smA/smB done
    if ((ct >> 3) == pass) {
      int cb = (ct & 7) * 8;
      #pragma unroll
      for (int l = 0; l < 8; ++l)
        #pragma unroll
        for (int j = 0; j < 8; ++j)
          smB[(cb + l) * 128 + rt * 8 + j] = s[j][l] * inv8[j];   // normalized P^T
    }
    for (int i = t; i < 1024; i += 256) {
      int row = i >> 4, c4 = i & 15;
      int ok = (int)(kk[pass * 64 + row] & 8191);
      *(float4*)&smA[row * 64 + c4 * 4] = *(const float4*)(Vb + (size_t)ok * DIM + c4 * 4);
    }
    __syncthreads();
    #pragma unroll 4
    for (int cc2 = 0; cc2 < 32; ++cc2) {
      int ccl = cc2 * 2 + par;
      float4 pa = *(const float4*)&smB[ccl * 128 + rt * 8];
      float4 pb = *(const float4*)&smB[ccl * 128 + rt * 8 + 4];
      float4 va = *(const float4*)&smA[ccl * 64 + ct8 * 8];
      float4 vb = *(const float4*)&smA[ccl * 64 + ct8 * 8 + 4];
      float pv[8] = {pa.x, pa.y, pa.z, pa.w, pb.x, pb.y, pb.z, pb.w};
      float vv[8] = {va.x, va.y, va.z, va.w, vb.x, vb.y, vb.z, vb.w};
      #pragma unroll
      for (int j = 0; j < 8; ++j)
        #pragma unroll
        for (int l = 0; l < 8; ++l) acc[j][l] = fmaf(pv[j], vv[l], acc[j][l]);
    }
  }
  // reduce across parity partner, then scatter rows to original token order
  #pragma unroll
  for (int j = 0; j < 8; ++j)
    #pragma unroll
    for (int l = 0; l < 8; ++l) acc[j][l] += __shfl_xor(acc[j][l], 8);
  float* bo = (float*)((char*)ws + WS_BO_B);
  #pragma unroll
  for (int j = 0; j < 8; ++j) {
    int oq = (int)(qk[rt * 8 + j] & 8191);
    float* orow = bo + ((((size_t)h * BATCH + b) << 13) + oq) * 64 + ct8 * 8;
    float4 o;
    if (par == 0) { o.x = acc[j][0]; o.y = acc[j][1]; o.z = acc[j][2]; o.w = acc[j][3]; *(float4*)orow = o; }
    else          { o.x = acc[j][4]; o.y = acc[j][5]; o.z = acc[j][6]; o.w = acc[j][7]; *(float4*)(orow + 4) = o; }
  }
}

// ---------------- k_combine: softmax over hashes by lse, weighted sum ----------------
__global__ __launch_bounds__(256) void smyrf_combine(const float* __restrict__ ws,
                                                     float* __restrict__ out) {
  int tid = blockIdx.x * 256 + threadIdx.x;   // 524288 float4s
  int f4i = tid & 15;
  int n = (tid >> 4) & 8191;
  int b = tid >> 17;
  const float* lse = (const float*)((const char*)ws + WS_LSE_B);
  const float* bo  = (const float*)((const char*)ws + WS_BO_B);
  float l[8];
  #pragma unroll
  for (int hh = 0; hh < 8; ++hh) l[hh] = lse[(((size_t)hh * BATCH + b) << 13) + n];
  float m = l[0];
  #pragma unroll
  for (int hh = 1; hh < 8; ++hh) m = fmaxf(m, l[hh]);
  float w[8]; float sum = 0.0f;
  #pragma unroll
  for (int hh = 0; hh < 8; ++hh) { w[hh] = __expf(l[hh] - m); sum += w[hh]; }
  float inv = 1.0f / sum;
  float4 a; a.x = a.y = a.z = a.w = 0.0f;
  #pragma unroll
  for (int hh = 0; hh < 8; ++hh) {
    const float4* p = (const float4*)(bo + ((((size_t)hh * BATCH + b) << 13) + n) * 64) + f4i;
    float4 v = *p;
    float ww = w[hh] * inv;
    a.x = fmaf(ww, v.x, a.x); a.y = fmaf(ww, v.y, a.y);
    a.z = fmaf(ww, v.z, a.z); a.w = fmaf(ww, v.w, a.w);
  }
  ((float4*)out)[tid] = a;
}

// ---------------- launch ----------------
extern "C" void kernel_launch(void* const* d_in, const int* in_sizes, int n_in,
                              void* d_out, int out_size, void* d_ws, size_t ws_size,
                              hipStream_t stream) {
  const float* q = (const float*)d_in[0];
  const float* k = (const float*)d_in[1];
  const float* v = (const float*)d_in[2];
  float* out = (float*)d_out;
  float* ws = (float*)d_ws;   // needs ~70.6 MB

  smyrf_rng<<<1, 256, 0, stream>>>(ws);
  smyrf_norms<<<256, 256, 0, stream>>>(q, k, ws);
  smyrf_keys<<<256, 256, 0, stream>>>(q, k, ws);
  smyrf_sort<<<64, 1024, 0, stream>>>(ws);
  smyrf_attn<<<NH * BATCH * NCLU, 256, 0, stream>>>(q, k, v, ws);
  smyrf_combine<<<2048, 256, 0, stream>>>(ws, out);
}

// Round 2
// 374.868 us; speedup vs baseline: 2.9819x; 2.9819x over previous
//
#include <hip/hip_runtime.h>
#include <stdint.h>

typedef unsigned int u32;
typedef unsigned long long u64;

// ---------------- problem constants ----------------
#define BATCH 4
#define NSEQ  8192
#define DIM   64
#define NH    8
#define CSZ   128   // cluster size (Q_ATTN == K_ATTN)
#define NCLU  64    // clusters per (h,b)

// JAX threefry bit-derivation scheme: 1 = partitionable, bits = x0^x1 (verified R1: absmax 0.0156 PASS)
#define RNG_SCHEME 1

// ---------------- workspace layout ----------------
// float-index offsets unless noted _B (bytes)
#define WS_ALPHA   0          // alpha[8][66] f32 (528)
#define WS_BETA    528        // beta[8] f32
#define WS_MAXB    536        // maxnorm bits [2][4] u32
#define WS_QN      1024       // qn[2][4][8192] f32  (65536)
#define WS_KEYS_B  266240     // keys[2][8][4][8192] u32 (2 MiB), sorted in place
#define WS_LSE_B   2363392    // lse[8][4][8192] f32 (1 MiB)
#define WS_BO_B    3411968    // bo[8][4][8192][64] f32 (64 MiB)
// total = 70,520,832 bytes

// ---------------- Threefry-2x32 (JAX) ----------------
__device__ __forceinline__ void tf2x32(u32 k0, u32 k1, u32 x0, u32 x1, u32& o0, u32& o1) {
  u32 ks2 = k0 ^ k1 ^ 0x1BD11BDAu;
  x0 += k0; x1 += k1;
#define TF_RND(r) { x0 += x1; x1 = (x1 << (r)) | (x1 >> (32 - (r))); x1 ^= x0; }
  TF_RND(13) TF_RND(15) TF_RND(26) TF_RND(6)
  x0 += k1; x1 += ks2 + 1u;
  TF_RND(17) TF_RND(29) TF_RND(16) TF_RND(24)
  x0 += ks2; x1 += k0 + 2u;
  TF_RND(13) TF_RND(15) TF_RND(26) TF_RND(6)
  x0 += k0; x1 += k1 + 3u;
  TF_RND(17) TF_RND(29) TF_RND(16) TF_RND(24)
  x0 += k1; x1 += ks2 + 4u;
  TF_RND(13) TF_RND(15) TF_RND(26) TF_RND(6)
  x0 += ks2; x1 += k0 + 5u;
#undef TF_RND
  o0 = x0; o1 = x1;
}

// JAX uniform [0,1): bitcast((bits>>9)|0x3f800000) - 1.0  (exact subtraction)
__device__ __forceinline__ float bits01(u32 b) {
  return __uint_as_float((b >> 9) | 0x3f800000u) - 1.0f;
}

// XLA ErfInv32 (Giles polynomial), exact fp32 op sequence (no FMA contraction).
__device__ __forceinline__ float xla_erfinv(float x) {
  float x2 = __fmul_rn(x, x);
  float w = (float)(-log1p(-(double)x2));   // log1p in f64, round once (<=1ulp vs XLA)
  float p;
  if (w < 5.0f) {
    float ww = __fsub_rn(w, 2.5f);
    p = 2.81022636e-08f;
    p = __fadd_rn(3.43273939e-07f, __fmul_rn(p, ww));
    p = __fadd_rn(-3.5233877e-06f, __fmul_rn(p, ww));
    p = __fadd_rn(-4.39150654e-06f, __fmul_rn(p, ww));
    p = __fadd_rn(0.00021858087f, __fmul_rn(p, ww));
    p = __fadd_rn(-0.00125372503f, __fmul_rn(p, ww));
    p = __fadd_rn(-0.00417768164f, __fmul_rn(p, ww));
    p = __fadd_rn(0.246640727f, __fmul_rn(p, ww));
    p = __fadd_rn(1.50140941f, __fmul_rn(p, ww));
  } else {
    float ww = __fsub_rn(__fsqrt_rn(w), 3.0f);
    p = -0.000200214257f;
    p = __fadd_rn(0.000100950558f, __fmul_rn(p, ww));
    p = __fadd_rn(0.00134934322f, __fmul_rn(p, ww));
    p = __fadd_rn(-0.00367342844f, __fmul_rn(p, ww));
    p = __fadd_rn(0.00573950773f, __fmul_rn(p, ww));
    p = __fadd_rn(-0.0076224613f, __fmul_rn(p, ww));
    p = __fadd_rn(0.00943887047f, __fmul_rn(p, ww));
    p = __fadd_rn(1.00167406f, __fmul_rn(p, ww));
    p = __fadd_rn(2.83297682f, __fmul_rn(p, ww));
  }
  return __fmul_rn(p, x);
}

// ---------------- k_rng: alpha/beta constants + zero max-norm slots ----------------
__global__ __launch_bounds__(256) void smyrf_rng(float* ws) {
  int t = threadIdx.x;
  float* alpha = ws + WS_ALPHA;
  float* beta  = ws + WS_BETA;
  u32*   maxb  = (u32*)(ws + WS_MAXB);
  if (t < 8) maxb[t] = 0u;                 // d_ws is poisoned each call
  u32 ka0, ka1, kb0, kb1;
  tf2x32(0u, 42u, 0u, 0u, ka0, ka1);       // fold_in(key(42), 0)
  tf2x32(0u, 42u, 0u, 1u, kb0, kb1);       // fold_in(key(42), 1)
  const float LO = __uint_as_float(0xBF7FFFFFu);   // nextafter(-1,0)
  const float SQ2 = 1.4142135623730951f;           // rounds to fp32 sqrt(2)
  for (int i = t; i < 528; i += 256) {
    u32 o0, o1; tf2x32(ka0, ka1, 0u, (u32)i, o0, o1);
    u32 bits = o0 ^ o1;
    float u = __fadd_rn(__fmul_rn(bits01(bits), 2.0f), LO);
    alpha[i] = __fmul_rn(SQ2, xla_erfinv(u));
  }
  if (t < 8) {
    u32 o0, o1; tf2x32(kb0, kb1, 0u, (u32)t, o0, o1);
    beta[t] = bits01(o0 ^ o1);
  }
}

// ---------------- k_norms: per-token ||x||; block-reduced max (R1 fix: was 65536
// per-thread atomicMax onto 8 words -> TCC serialization, 748us. Now 1 atomic/block.)
__global__ __launch_bounds__(256) void smyrf_norms(const float* __restrict__ Q,
                                                   const float* __restrict__ Kk,
                                                   float* ws) {
  int tid = blockIdx.x * 256 + threadIdx.x;        // 65536 = 2*4*8192
  int tensor = tid >> 15;
  const float* x = (tensor ? Kk : Q) + (size_t)(tid & 32767) * DIM;
  const float4* x4 = (const float4*)x;
  double s = 0.0;
  #pragma unroll
  for (int i = 0; i < 16; ++i) {
    float4 v = x4[i];
    s += (double)v.x * v.x + (double)v.y * v.y + (double)v.z * v.z + (double)v.w * v.w;
  }
  float qn = (float)sqrt(s);
  (ws + WS_QN)[tid] = qn;
  // block covers 256 consecutive tokens of one (tensor,b) segment -> reduce then 1 atomic
  float wmax = qn;
  #pragma unroll
  for (int off = 1; off < 64; off <<= 1) wmax = fmaxf(wmax, __shfl_xor(wmax, off));
  __shared__ float red[4];
  int wave = threadIdx.x >> 6;
  if ((threadIdx.x & 63) == 0) red[wave] = wmax;
  __syncthreads();
  if (threadIdx.x == 0) {
    float m = fmaxf(fmaxf(red[0], red[1]), fmaxf(red[2], red[3]));
    int b = (tid >> 13) & 3;
    atomicMax((u32*)(ws + WS_MAXB) + tensor * 4 + b, __float_as_uint(m));
  }
}

// ---------------- k_keys: E2LSH bucket -> stable-sort key (bucket<<13 | idx) ----------------
__global__ __launch_bounds__(256) void smyrf_keys(const float* __restrict__ Q,
                                                  const float* __restrict__ Kk,
                                                  float* ws) {
  int tid = blockIdx.x * 256 + threadIdx.x;        // 65536
  int tensor = tid >> 15;
  int b = (tid >> 13) & 3;
  int n = tid & 8191;
  const float* x = (tensor ? Kk : Q) + (size_t)(tid & 32767) * DIM;
  float r[64];
  const float4* x4 = (const float4*)x;
  #pragma unroll
  for (int i = 0; i < 16; ++i) {
    float4 v = x4[i];
    r[4 * i] = v.x; r[4 * i + 1] = v.y; r[4 * i + 2] = v.z; r[4 * i + 3] = v.w;
  }
  const float* alpha = ws + WS_ALPHA;
  const float* beta  = ws + WS_BETA;
  const u32*   maxb  = (const u32*)(ws + WS_MAXB);
  float qn = (ws + WS_QN)[tid];
  float mq = __uint_as_float(maxb[b]);
  float mk = __uint_as_float(maxb[4 + b]);
  float M2 = __fadd_rn(__fmul_rn(mq, mq), __fmul_rn(mk, mk));   // max_qn^2 + max_kn^2 (fp32)
  float ex = __fsqrt_rn(fmaxf(__fsub_rn(M2, __fmul_rn(qn, qn)), 0.0f));
  u32* keys = (u32*)((char*)ws + WS_KEYS_B);
  #pragma unroll 1
  for (int hh = 0; hh < NH; ++hh) {
    const float* al = alpha + hh * 66;
    double dot = 0.0;
    #pragma unroll
    for (int d = 0; d < 64; ++d) dot = fma((double)r[d], (double)al[d], dot);
    dot = fma((double)ex, (double)al[64 + tensor], dot);        // augmented coord (q:64, k:65)
    float val = __fadd_rn((float)dot, beta[hh]);                // fp32 round then +beta, /1.0
    float fb = floorf(val);
    int ib = (fb >= 262143.f) ? 262143 : ((fb <= -262144.f) ? -262144 : (int)fb);
    keys[((size_t)tensor * NH * BATCH + (size_t)hh * BATCH + b) * NSEQ + n] =
        ((u32)(ib + 262144) << 13) | (u32)n;                    // stable: idx in low 13 bits
  }
}

// ---------------- k_sort: in-LDS bitonic, one (tensor,h,b) segment per block ----------------
__global__ __launch_bounds__(1024) void smyrf_sort(float* ws) {
  __shared__ u32 arr[8192];
  u32* base = (u32*)((char*)ws + WS_KEYS_B) + (size_t)blockIdx.x * 8192;
  int t = threadIdx.x;
  for (int i = t; i < 8192; i += 1024) arr[i] = base[i];
  __syncthreads();
  for (int kk = 2; kk <= 8192; kk <<= 1) {
    for (int j = kk >> 1; j > 0; j >>= 1) {
      for (int i = t; i < 8192; i += 1024) {
        int ixj = i ^ j;
        if (ixj > i) {
          u32 A = arr[i], B = arr[ixj];
          bool up = (i & kk) == 0;
          if ((A > B) == up) { arr[i] = B; arr[ixj] = A; }
        }
      }
      __syncthreads();
    }
  }
  for (int i = t; i < 8192; i += 1024) base[i] = arr[i];
}

// ---------------- k_attn: per-cluster softmax attention (fp32 VALU), scatter to orig order ----
// block = 256 threads, one (h,b,c) cluster. 8x8 register tiles; P staged through LDS in 2 halves.
__global__ __launch_bounds__(256, 2) void smyrf_attn(const float* __restrict__ Q,
                                                     const float* __restrict__ K,
                                                     const float* __restrict__ V,
                                                     float* __restrict__ ws) {
  __shared__ float smA[64 * 128];  // Q^T [d][r]; later V half-tile [64][64] in first 4096
  __shared__ float smB[64 * 128];  // K^T [d][c]; later P half [cc_local][r]
  int id = blockIdx.x;
  int c = id & 63, b = (id >> 6) & 3, h = id >> 8;
  int t = threadIdx.x;

  const u32* keys = (const u32*)((const char*)ws + WS_KEYS_B);
  const u32* qk = keys + ((size_t)h * BATCH + b) * NSEQ + c * CSZ;
  const u32* kk = keys + (size_t)NH * BATCH * NSEQ + ((size_t)h * BATCH + b) * NSEQ + c * CSZ;
  const float* Qb = Q + (size_t)b * NSEQ * DIM;
  const float* Kb = K + (size_t)b * NSEQ * DIM;
  const float* Vb = V + (size_t)b * NSEQ * DIM;

  // stage Q^T / K^T: row = i&127 -> conflict-free LDS writes (bank = row%32, 2 lanes each)
  for (int i = t; i < 2048; i += 256) {
    int row = i & 127, c4 = i >> 7;
    int oq = (int)(qk[row] & 8191);
    float4 f = *(const float4*)(Qb + (size_t)oq * DIM + c4 * 4);
    smA[(c4 * 4 + 0) * 128 + row] = f.x;
    smA[(c4 * 4 + 1) * 128 + row] = f.y;
    smA[(c4 * 4 + 2) * 128 + row] = f.z;
    smA[(c4 * 4 + 3) * 128 + row] = f.w;
    int ok = (int)(kk[row] & 8191);
    float4 g = *(const float4*)(Kb + (size_t)ok * DIM + c4 * 4);
    smB[(c4 * 4 + 0) * 128 + row] = g.x;
    smB[(c4 * 4 + 1) * 128 + row] = g.y;
    smB[(c4 * 4 + 2) * 128 + row] = g.z;
    smB[(c4 * 4 + 3) * 128 + row] = g.w;
  }
  __syncthreads();

  // scores: thread (rt,ct) owns rows rt*8.., cols ct*8..
  int rt = t >> 4, ct = t & 15;
  float s[8][8];
  #pragma unroll
  for (int j = 0; j < 8; ++j)
    #pragma unroll
    for (int l = 0; l < 8; ++l) s[j][l] = 0.0f;
  #pragma unroll 2
  for (int d = 0; d < 64; ++d) {
    float4 qa = *(const float4*)&smA[d * 128 + rt * 8];
    float4 qb4 = *(const float4*)&smA[d * 128 + rt * 8 + 4];
    float4 ka = *(const float4*)&smB[d * 128 + ct * 8];
    float4 kb4 = *(const float4*)&smB[d * 128 + ct * 8 + 4];
    float qv[8] = {qa.x, qa.y, qa.z, qa.w, qb4.x, qb4.y, qb4.z, qb4.w};
    float kv[8] = {ka.x, ka.y, ka.z, ka.w, kb4.x, kb4.y, kb4.z, kb4.w};
    #pragma unroll
    for (int j = 0; j < 8; ++j)
      #pragma unroll
      for (int l = 0; l < 8; ++l) s[j][l] = fmaf(qv[j], kv[l], s[j][l]);
  }

  // softmax (full row present across the 16-lane ct group)
  float inv8[8];
  float* lse = (float*)((char*)ws + WS_LSE_B);
  #pragma unroll
  for (int j = 0; j < 8; ++j) {
    float m = s[j][0];
    #pragma unroll
    for (int l = 1; l < 8; ++l) m = fmaxf(m, s[j][l]);
    m = fmaxf(m, __shfl_xor(m, 1));
    m = fmaxf(m, __shfl_xor(m, 2));
    m = fmaxf(m, __shfl_xor(m, 4));
    m = fmaxf(m, __shfl_xor(m, 8));
    float sum = 0.0f;
    #pragma unroll
    for (int l = 0; l < 8; ++l) { s[j][l] = __expf(s[j][l] - m); sum += s[j][l]; }
    sum += __shfl_xor(sum, 1);
    sum += __shfl_xor(sum, 2);
    sum += __shfl_xor(sum, 4);
    sum += __shfl_xor(sum, 8);
    inv8[j] = 1.0f / sum;
    if (ct == 0) {
      int oq = (int)(qk[rt * 8 + j] & 8191);
      lse[(((size_t)h * BATCH + b) << 13) + oq] = m + __logf(sum);
    }
  }

  // PV in two cc-halves: P^T half in smB [64][128], V half in smA [64][64]
  float acc[8][8];
  #pragma unroll
  for (int j = 0; j < 8; ++j)
    #pragma unroll
    for (int l = 0; l < 8; ++l) acc[j][l] = 0.0f;
  int par = (t >> 3) & 1;   // cc parity; partner = t^8
  int ct8 = t & 7;          // dv tile (8 wide)
  #pragma unroll 1
  for (int pass = 0; pass < 2; ++pass) {
    __syncthreads();   // prior readers of smA/smB done
    if ((ct >> 3) == pass) {
      int cb = (ct & 7) * 8;
      #pragma unroll
      for (int l = 0; l < 8; ++l)
        #pragma unroll
        for (int j = 0; j < 8; ++j)
          smB[(cb + l) * 128 + rt * 8 + j] = s[j][l] * inv8[j];   // normalized P^T
    }
    for (int i = t; i < 1024; i += 256) {
      int row = i >> 4, c4 = i & 15;
      int ok = (int)(kk[pass * 64 + row] & 8191);
      *(float4*)&smA[row * 64 + c4 * 4] = *(const float4*)(Vb + (size_t)ok * DIM + c4 * 4);
    }
    __syncthreads();
    #pragma unroll 4
    for (int cc2 = 0; cc2 < 32; ++cc2) {
      int ccl = cc2 * 2 + par;
      float4 pa = *(const float4*)&smB[ccl * 128 + rt * 8];
      float4 pb = *(const float4*)&smB[ccl * 128 + rt * 8 + 4];
      float4 va = *(const float4*)&smA[ccl * 64 + ct8 * 8];
      float4 vb = *(const float4*)&smA[ccl * 64 + ct8 * 8 + 4];
      float pv[8] = {pa.x, pa.y, pa.z, pa.w, pb.x, pb.y, pb.z, pb.w};
      float vv[8] = {va.x, va.y, va.z, va.w, vb.x, vb.y, vb.z, vb.w};
      #pragma unroll
      for (int j = 0; j < 8; ++j)
        #pragma unroll
        for (int l = 0; l < 8; ++l) acc[j][l] = fmaf(pv[j], vv[l], acc[j][l]);
    }
  }
  // reduce across parity partner, then scatter rows to original token order
  #pragma unroll
  for (int j = 0; j < 8; ++j)
    #pragma unroll
    for (int l = 0; l < 8; ++l) acc[j][l] += __shfl_xor(acc[j][l], 8);
  float* bo = (float*)((char*)ws + WS_BO_B);
  #pragma unroll
  for (int j = 0; j < 8; ++j) {
    int oq = (int)(qk[rt * 8 + j] & 8191);
    float* orow = bo + ((((size_t)h * BATCH + b) << 13) + oq) * 64 + ct8 * 8;
    float4 o;
    if (par == 0) { o.x = acc[j][0]; o.y = acc[j][1]; o.z = acc[j][2]; o.w = acc[j][3]; *(float4*)orow = o; }
    else          { o.x = acc[j][4]; o.y = acc[j][5]; o.z = acc[j][6]; o.w = acc[j][7]; *(float4*)(orow + 4) = o; }
  }
}

// ---------------- k_combine: softmax over hashes by lse, weighted sum ----------------
__global__ __launch_bounds__(256) void smyrf_combine(const float* __restrict__ ws,
                                                     float* __restrict__ out) {
  int tid = blockIdx.x * 256 + threadIdx.x;   // 524288 float4s
  int f4i = tid & 15;
  int n = (tid >> 4) & 8191;
  int b = tid >> 17;
  const float* lse = (const float*)((const char*)ws + WS_LSE_B);
  const float* bo  = (const float*)((const char*)ws + WS_BO_B);
  float l[8];
  #pragma unroll
  for (int hh = 0; hh < 8; ++hh) l[hh] = lse[(((size_t)hh * BATCH + b) << 13) + n];
  float m = l[0];
  #pragma unroll
  for (int hh = 1; hh < 8; ++hh) m = fmaxf(m, l[hh]);
  float w[8]; float sum = 0.0f;
  #pragma unroll
  for (int hh = 0; hh < 8; ++hh) { w[hh] = __expf(l[hh] - m); sum += w[hh]; }
  float inv = 1.0f / sum;
  float4 a; a.x = a.y = a.z = a.w = 0.0f;
  #pragma unroll
  for (int hh = 0; hh < 8; ++hh) {
    const float4* p = (const float4*)(bo + ((((size_t)hh * BATCH + b) << 13) + n) * 64) + f4i;
    float4 v = *p;
    float ww = w[hh] * inv;
    a.x = fmaf(ww, v.x, a.x); a.y = fmaf(ww, v.y, a.y);
    a.z = fmaf(ww, v.z, a.z); a.w = fmaf(ww, v.w, a.w);
  }
  ((float4*)out)[tid] = a;
}

// ---------------- launch ----------------
extern "C" void kernel_launch(void* const* d_in, const int* in_sizes, int n_in,
                              void* d_out, int out_size, void* d_ws, size_t ws_size,
                              hipStream_t stream) {
  const float* q = (const float*)d_in[0];
  const float* k = (const float*)d_in[1];
  const float* v = (const float*)d_in[2];
  float* out = (float*)d_out;
  float* ws = (float*)d_ws;   // needs ~70.6 MB

  smyrf_rng<<<1, 256, 0, stream>>>(ws);
  smyrf_norms<<<256, 256, 0, stream>>>(q, k, ws);
  smyrf_keys<<<256, 256, 0, stream>>>(q, k, ws);
  smyrf_sort<<<64, 1024, 0, stream>>>(ws);
  smyrf_attn<<<NH * BATCH * NCLU, 256, 0, stream>>>(q, k, v, ws);
  smyrf_combine<<<2048, 256, 0, stream>>>(ws, out);
}

// Round 4
// 276.111 us; speedup vs baseline: 4.0484x; 1.3577x over previous
//
#include <hip/hip_runtime.h>
#include <stdint.h>

typedef unsigned int u32;
typedef unsigned long long u64;

// ---------------- problem constants ----------------
#define BATCH 4
#define NSEQ  8192
#define DIM   64
#define NH    8
#define CSZ   128
#define NCLU  64

// ---------------- workspace layout ----------------
#define WS_ALPHA   0
#define WS_BETA    528
#define WS_MAXB    536
#define WS_QN      1024
#define WS_KEYS_B  266240
#define WS_LSE_B   2363392
#define WS_BO_B    3411968
// total = 70,520,832 bytes

typedef short bf16x8 __attribute__((ext_vector_type(8)));
typedef float f32x4 __attribute__((ext_vector_type(4)));
#define MFMA16(a, b, c) __builtin_amdgcn_mfma_f32_16x16x32_bf16(a, b, c, 0, 0, 0)

// ---------------- Threefry-2x32 (JAX) ----------------
__device__ __forceinline__ void tf2x32(u32 k0, u32 k1, u32 x0, u32 x1, u32& o0, u32& o1) {
  u32 ks2 = k0 ^ k1 ^ 0x1BD11BDAu;
  x0 += k0; x1 += k1;
#define TF_RND(r) { x0 += x1; x1 = (x1 << (r)) | (x1 >> (32 - (r))); x1 ^= x0; }
  TF_RND(13) TF_RND(15) TF_RND(26) TF_RND(6)
  x0 += k1; x1 += ks2 + 1u;
  TF_RND(17) TF_RND(29) TF_RND(16) TF_RND(24)
  x0 += ks2; x1 += k0 + 2u;
  TF_RND(13) TF_RND(15) TF_RND(26) TF_RND(6)
  x0 += k0; x1 += k1 + 3u;
  TF_RND(17) TF_RND(29) TF_RND(16) TF_RND(24)
  x0 += k1; x1 += ks2 + 4u;
  TF_RND(13) TF_RND(15) TF_RND(26) TF_RND(6)
  x0 += ks2; x1 += k0 + 5u;
#undef TF_RND
  o0 = x0; o1 = x1;
}

__device__ __forceinline__ float bits01(u32 b) {
  return __uint_as_float((b >> 9) | 0x3f800000u) - 1.0f;
}

__device__ __forceinline__ float xla_erfinv(float x) {
  float x2 = __fmul_rn(x, x);
  float w = (float)(-log1p(-(double)x2));
  float p;
  if (w < 5.0f) {
    float ww = __fsub_rn(w, 2.5f);
    p = 2.81022636e-08f;
    p = __fadd_rn(3.43273939e-07f, __fmul_rn(p, ww));
    p = __fadd_rn(-3.5233877e-06f, __fmul_rn(p, ww));
    p = __fadd_rn(-4.39150654e-06f, __fmul_rn(p, ww));
    p = __fadd_rn(0.00021858087f, __fmul_rn(p, ww));
    p = __fadd_rn(-0.00125372503f, __fmul_rn(p, ww));
    p = __fadd_rn(-0.00417768164f, __fmul_rn(p, ww));
    p = __fadd_rn(0.246640727f, __fmul_rn(p, ww));
    p = __fadd_rn(1.50140941f, __fmul_rn(p, ww));
  } else {
    float ww = __fsub_rn(__fsqrt_rn(w), 3.0f);
    p = -0.000200214257f;
    p = __fadd_rn(0.000100950558f, __fmul_rn(p, ww));
    p = __fadd_rn(0.00134934322f, __fmul_rn(p, ww));
    p = __fadd_rn(-0.00367342844f, __fmul_rn(p, ww));
    p = __fadd_rn(0.00573950773f, __fmul_rn(p, ww));
    p = __fadd_rn(-0.0076224613f, __fmul_rn(p, ww));
    p = __fadd_rn(0.00943887047f, __fmul_rn(p, ww));
    p = __fadd_rn(1.00167406f, __fmul_rn(p, ww));
    p = __fadd_rn(2.83297682f, __fmul_rn(p, ww));
  }
  return __fmul_rn(p, x);
}

// ---------------- k_rng ----------------
__global__ __launch_bounds__(256) void smyrf_rng(float* ws) {
  int t = threadIdx.x;
  float* alpha = ws + WS_ALPHA;
  float* beta  = ws + WS_BETA;
  u32*   maxb  = (u32*)(ws + WS_MAXB);
  if (t < 8) maxb[t] = 0u;
  u32 ka0, ka1, kb0, kb1;
  tf2x32(0u, 42u, 0u, 0u, ka0, ka1);
  tf2x32(0u, 42u, 0u, 1u, kb0, kb1);
  const float LO = __uint_as_float(0xBF7FFFFFu);
  const float SQ2 = 1.4142135623730951f;
  for (int i = t; i < 528; i += 256) {
    u32 o0, o1; tf2x32(ka0, ka1, 0u, (u32)i, o0, o1);
    u32 bits = o0 ^ o1;
    float u = __fadd_rn(__fmul_rn(bits01(bits), 2.0f), LO);
    alpha[i] = __fmul_rn(SQ2, xla_erfinv(u));
  }
  if (t < 8) {
    u32 o0, o1; tf2x32(kb0, kb1, 0u, (u32)t, o0, o1);
    beta[t] = bits01(o0 ^ o1);
  }
}

// ---------------- k_norms (R1 fix: block-reduced atomicMax) ----------------
__global__ __launch_bounds__(256) void smyrf_norms(const float* __restrict__ Q,
                                                   const float* __restrict__ Kk,
                                                   float* ws) {
  int tid = blockIdx.x * 256 + threadIdx.x;
  int tensor = tid >> 15;
  const float* x = (tensor ? Kk : Q) + (size_t)(tid & 32767) * DIM;
  const float4* x4 = (const float4*)x;
  double s = 0.0;
  #pragma unroll
  for (int i = 0; i < 16; ++i) {
    float4 v = x4[i];
    s += (double)v.x * v.x + (double)v.y * v.y + (double)v.z * v.z + (double)v.w * v.w;
  }
  float qn = (float)sqrt(s);
  (ws + WS_QN)[tid] = qn;
  float wmax = qn;
  #pragma unroll
  for (int off = 1; off < 64; off <<= 1) wmax = fmaxf(wmax, __shfl_xor(wmax, off));
  __shared__ float red[4];
  int wave = threadIdx.x >> 6;
  if ((threadIdx.x & 63) == 0) red[wave] = wmax;
  __syncthreads();
  if (threadIdx.x == 0) {
    float m = fmaxf(fmaxf(red[0], red[1]), fmaxf(red[2], red[3]));
    int b = (tid >> 13) & 3;
    atomicMax((u32*)(ws + WS_MAXB) + tensor * 4 + b, __float_as_uint(m));
  }
}

// ---------------- k_keys ----------------
__global__ __launch_bounds__(256) void smyrf_keys(const float* __restrict__ Q,
                                                  const float* __restrict__ Kk,
                                                  float* ws) {
  int tid = blockIdx.x * 256 + threadIdx.x;
  int tensor = tid >> 15;
  int b = (tid >> 13) & 3;
  int n = tid & 8191;
  const float* x = (tensor ? Kk : Q) + (size_t)(tid & 32767) * DIM;
  float r[64];
  const float4* x4 = (const float4*)x;
  #pragma unroll
  for (int i = 0; i < 16; ++i) {
    float4 v = x4[i];
    r[4 * i] = v.x; r[4 * i + 1] = v.y; r[4 * i + 2] = v.z; r[4 * i + 3] = v.w;
  }
  const float* alpha = ws + WS_ALPHA;
  const float* beta  = ws + WS_BETA;
  const u32*   maxb  = (const u32*)(ws + WS_MAXB);
  float qn = (ws + WS_QN)[tid];
  float mq = __uint_as_float(maxb[b]);
  float mk = __uint_as_float(maxb[4 + b]);
  float M2 = __fadd_rn(__fmul_rn(mq, mq), __fmul_rn(mk, mk));
  float ex = __fsqrt_rn(fmaxf(__fsub_rn(M2, __fmul_rn(qn, qn)), 0.0f));
  u32* keys = (u32*)((char*)ws + WS_KEYS_B);
  #pragma unroll 1
  for (int hh = 0; hh < NH; ++hh) {
    const float* al = alpha + hh * 66;
    double dot = 0.0;
    #pragma unroll
    for (int d = 0; d < 64; ++d) dot = fma((double)r[d], (double)al[d], dot);
    dot = fma((double)ex, (double)al[64 + tensor], dot);
    float val = __fadd_rn((float)dot, beta[hh]);
    float fb = floorf(val);
    int ib = (fb >= 262143.f) ? 262143 : ((fb <= -262144.f) ? -262144 : (int)fb);
    keys[((size_t)tensor * NH * BATCH + (size_t)hh * BATCH + b) * NSEQ + n] =
        ((u32)(ib + 262144) << 13) | (u32)n;
  }
}

// ---------------- k_sort: in-LDS bitonic ----------------
__global__ __launch_bounds__(1024) void smyrf_sort(float* ws) {
  __shared__ u32 arr[8192];
  u32* base = (u32*)((char*)ws + WS_KEYS_B) + (size_t)blockIdx.x * 8192;
  int t = threadIdx.x;
  for (int i = t; i < 8192; i += 1024) arr[i] = base[i];
  __syncthreads();
  for (int kk = 2; kk <= 8192; kk <<= 1) {
    for (int j = kk >> 1; j > 0; j >>= 1) {
      for (int i = t; i < 8192; i += 1024) {
        int ixj = i ^ j;
        if (ixj > i) {
          u32 A = arr[i], B = arr[ixj];
          bool up = (i & kk) == 0;
          if ((A > B) == up) { arr[i] = B; arr[ixj] = A; }
        }
      }
      __syncthreads();
    }
  }
  for (int i = t; i < 8192; i += 1024) base[i] = arr[i];
}

// ---------------- k_attn (R2 rewrite): MFMA split-bf16 ----------------
// Block = 256 thr / 4 waves, one (h,b,c) cluster. QK^T: 3-term split-bf16
// (err ~2^-18); PV: O^T = V^T * P^T, both split. LDS 64KB peak:
//   phase 1: Qhi|Qlo [0,32K), Khi|Klo [32K,64K)   (128 rows x 64k bf16, 128B rows)
//   phase 2: Phi|Plo(half) [0,32K), VThi|VTlo [32K,64K)  (VT: 64 rows x 128k, 256B rows)
// Swizzle: 128B rows byte^=(row&7)<<4; 256B rows byte^=(row&7)<<5 (G4 fix).
__device__ __forceinline__ ushort f2bf(float x) {
  u32 xb = __float_as_uint(x);
  return (ushort)((xb + 0x7FFFu + ((xb >> 16) & 1u)) >> 16);
}
__device__ __forceinline__ float bf2f(ushort h) { return __uint_as_float(((u32)h) << 16); }
__device__ __forceinline__ int swz(int row, int kb) { return row * 128 + (kb ^ ((row & 7) << 4)); }

__global__ __launch_bounds__(256) void smyrf_attn_mfma(const float* __restrict__ Q,
                                                       const float* __restrict__ K,
                                                       const float* __restrict__ V,
                                                       float* __restrict__ ws) {
  __shared__ uint4 smem_u4[4096];   // 64 KB
  char* sm = (char*)smem_u4;
  int id = blockIdx.x;
  int c = id & 63, b = (id >> 6) & 3, h = id >> 8;
  int t = threadIdx.x;
  int lane = t & 63, w = t >> 6;
  int cl = lane & 15, ag = lane >> 4;

  const u32* keys = (const u32*)((const char*)ws + WS_KEYS_B);
  const u32* qkp = keys + ((size_t)h * BATCH + b) * NSEQ + c * CSZ;
  const u32* kkp = keys + (size_t)NH * BATCH * NSEQ + ((size_t)h * BATCH + b) * NSEQ + c * CSZ;
  const float* Qb = Q + (size_t)b * NSEQ * DIM;
  const float* Kb = K + (size_t)b * NSEQ * DIM;
  const float* Vb = V + (size_t)b * NSEQ * DIM;

  // ---- stage Q,K as hi/lo bf16 planes ----
  {
    int row = t & 127;
    int tensor = t >> 7;                   // 0=Q, 1=K
    int tok = (int)((tensor ? kkp[row] : qkp[row]) & 8191);
    const float* src = (tensor ? Kb : Qb) + (size_t)tok * DIM;
    char* hb = sm + tensor * 32768;
    char* lb = hb + 16384;
    int sw = (row & 7) << 4;
    #pragma unroll
    for (int c8 = 0; c8 < 8; ++c8) {
      float4 a = *(const float4*)(src + c8 * 8);
      float4 cc = *(const float4*)(src + c8 * 8 + 4);
      float v[8] = {a.x, a.y, a.z, a.w, cc.x, cc.y, cc.z, cc.w};
      ushort hh[8], ll[8];
      #pragma unroll
      for (int j = 0; j < 8; ++j) { hh[j] = f2bf(v[j]); ll[j] = f2bf(v[j] - bf2f(hh[j])); }
      uint4 hv, lv;
      hv.x = (u32)hh[0] | ((u32)hh[1] << 16); hv.y = (u32)hh[2] | ((u32)hh[3] << 16);
      hv.z = (u32)hh[4] | ((u32)hh[5] << 16); hv.w = (u32)hh[6] | ((u32)hh[7] << 16);
      lv.x = (u32)ll[0] | ((u32)ll[1] << 16); lv.y = (u32)ll[2] | ((u32)ll[3] << 16);
      lv.z = (u32)ll[4] | ((u32)ll[5] << 16); lv.w = (u32)ll[6] | ((u32)ll[7] << 16);
      int off = row * 128 + ((c8 * 16) ^ sw);
      *(uint4*)&hb[off] = hv;
      *(uint4*)&lb[off] = lv;
    }
  }
  __syncthreads();

  // ---- QK^T: S[q][k], wave w owns q in [32w,32w+32) ----
  f32x4 S[2][8];
  #pragma unroll
  for (int m = 0; m < 2; ++m)
    #pragma unroll
    for (int n = 0; n < 8; ++n) S[m][n] = (f32x4){0.f, 0.f, 0.f, 0.f};
  {
    const char* Qhi = sm, *Qlo = sm + 16384, *Khi = sm + 32768, *Klo = sm + 49152;
    #pragma unroll
    for (int kk_ = 0; kk_ < 2; ++kk_) {
      int kb = kk_ * 64 + ag * 16;
      bf16x8 qh0 = *(const bf16x8*)&Qhi[swz(w * 32 + cl, kb)];
      bf16x8 qh1 = *(const bf16x8*)&Qhi[swz(w * 32 + 16 + cl, kb)];
      bf16x8 ql0 = *(const bf16x8*)&Qlo[swz(w * 32 + cl, kb)];
      bf16x8 ql1 = *(const bf16x8*)&Qlo[swz(w * 32 + 16 + cl, kb)];
      #pragma unroll
      for (int n = 0; n < 8; ++n) {
        int o = swz(n * 16 + cl, kb);
        bf16x8 kh = *(const bf16x8*)&Khi[o];
        bf16x8 kl = *(const bf16x8*)&Klo[o];
        S[0][n] = MFMA16(qh0, kh, S[0][n]);
        S[1][n] = MFMA16(qh1, kh, S[1][n]);
        S[0][n] = MFMA16(qh0, kl, S[0][n]);
        S[1][n] = MFMA16(qh1, kl, S[1][n]);
        S[0][n] = MFMA16(ql0, kh, S[0][n]);
        S[1][n] = MFMA16(ql1, kh, S[1][n]);
      }
    }
  }

  // ---- softmax: C/D layout row=(ag*4+reg), col=cl; row-reduce over 16 col-lanes ----
  float inv_[2][4];
  float* lse = (float*)((char*)ws + WS_LSE_B);
  #pragma unroll
  for (int m = 0; m < 2; ++m)
    #pragma unroll
    for (int r = 0; r < 4; ++r) {
      float mx = S[m][0][r];
      #pragma unroll
      for (int n = 1; n < 8; ++n) mx = fmaxf(mx, S[m][n][r]);
      mx = fmaxf(mx, __shfl_xor(mx, 1));
      mx = fmaxf(mx, __shfl_xor(mx, 2));
      mx = fmaxf(mx, __shfl_xor(mx, 4));
      mx = fmaxf(mx, __shfl_xor(mx, 8));
      float sum = 0.f;
      #pragma unroll
      for (int n = 0; n < 8; ++n) { float e = __expf(S[m][n][r] - mx); S[m][n][r] = e; sum += e; }
      sum += __shfl_xor(sum, 1);
      sum += __shfl_xor(sum, 2);
      sum += __shfl_xor(sum, 4);
      sum += __shfl_xor(sum, 8);
      inv_[m][r] = 1.0f / sum;
      if (cl == 0) {
        int q = w * 32 + m * 16 + ag * 4 + r;
        lse[(((size_t)h * BATCH + b) << 13) + (qkp[q] & 8191)] = mx + __logf(sum);
      }
    }

  // ---- PV in two k-halves: O^T[dv][q] accumulates across halves ----
  f32x4 O[4][2];
  #pragma unroll
  for (int mt = 0; mt < 4; ++mt)
    #pragma unroll
    for (int nt = 0; nt < 2; ++nt) O[mt][nt] = (f32x4){0.f, 0.f, 0.f, 0.f};

  #pragma unroll
  for (int half = 0; half < 2; ++half) {
    __syncthreads();   // all waves done reading LDS (QK frags / prev PV half)
    // write normalized P-half (hi/lo) into [0,32K)
    #pragma unroll
    for (int m = 0; m < 2; ++m)
      #pragma unroll
      for (int r = 0; r < 4; ++r) {
        int row = w * 32 + m * 16 + ag * 4 + r;
        int sw2 = (row & 7) << 4;
        float iv = inv_[m][r];
        #pragma unroll
        for (int n4 = 0; n4 < 4; ++n4) {
          float p = S[m][half * 4 + n4][r] * iv;
          ushort ph = f2bf(p);
          ushort pl = f2bf(p - bf2f(ph));
          int off = row * 128 + ((2 * (n4 * 16 + cl)) ^ sw2);
          *(ushort*)&sm[off] = ph;
          *(ushort*)&sm[16384 + off] = pl;
        }
      }
    if (half == 0) {   // stage V^T (full k) into [32K,64K)
      int tok = t >> 1, dh = (t & 1) * 32;
      const float* vs = Vb + (size_t)(kkp[tok] & 8191) * DIM + dh;
      #pragma unroll
      for (int c4 = 0; c4 < 8; ++c4) {
        float4 a = *(const float4*)(vs + c4 * 4);
        float vv[4] = {a.x, a.y, a.z, a.w};
        #pragma unroll
        for (int j = 0; j < 4; ++j) {
          int dv = dh + c4 * 4 + j;
          ushort vh = f2bf(vv[j]);
          ushort vl = f2bf(vv[j] - bf2f(vh));
          int off = dv * 256 + ((2 * tok) ^ ((dv & 7) << 5));
          *(ushort*)&sm[32768 + off] = vh;
          *(ushort*)&sm[49152 + off] = vl;
        }
      }
    }
    __syncthreads();
    #pragma unroll
    for (int k2 = 0; k2 < 2; ++k2) {
      int kbP = k2 * 64 + ag * 16;                 // bytes within P half-row (128B)
      int kbV = half * 128 + k2 * 64 + ag * 16;    // bytes within VT row (256B)
      bf16x8 p0h = *(const bf16x8*)&sm[swz(w * 32 + cl, kbP)];
      bf16x8 p0l = *(const bf16x8*)&sm[16384 + swz(w * 32 + cl, kbP)];
      bf16x8 p1h = *(const bf16x8*)&sm[swz(w * 32 + 16 + cl, kbP)];
      bf16x8 p1l = *(const bf16x8*)&sm[16384 + swz(w * 32 + 16 + cl, kbP)];
      #pragma unroll
      for (int mt = 0; mt < 4; ++mt) {
        int dv = mt * 16 + cl;
        int off = dv * 256 + (kbV ^ ((dv & 7) << 5));
        bf16x8 vh = *(const bf16x8*)&sm[32768 + off];
        bf16x8 vl = *(const bf16x8*)&sm[49152 + off];
        O[mt][0] = MFMA16(vh, p0h, O[mt][0]);
        O[mt][0] = MFMA16(vh, p0l, O[mt][0]);
        O[mt][0] = MFMA16(vl, p0h, O[mt][0]);
        O[mt][1] = MFMA16(vh, p1h, O[mt][1]);
        O[mt][1] = MFMA16(vh, p1l, O[mt][1]);
        O[mt][1] = MFMA16(vl, p1h, O[mt][1]);
      }
    }
  }

  // ---- epilogue: O^T lane holds dv=16mt+ag*4+reg (4 consecutive -> float4), q=32w+16nt+cl ----
  float* bo = (float*)((char*)ws + WS_BO_B);
  #pragma unroll
  for (int nt = 0; nt < 2; ++nt) {
    int q = w * 32 + nt * 16 + cl;
    int tok = (int)(qkp[q] & 8191);
    float* orow = bo + ((((size_t)h * BATCH + b) << 13) + tok) * 64;
    #pragma unroll
    for (int mt = 0; mt < 4; ++mt) {
      *(f32x4*)&orow[mt * 16 + ag * 4] = O[mt][nt];
    }
  }
}

// ---------------- k_combine ----------------
__global__ __launch_bounds__(256) void smyrf_combine(const float* __restrict__ ws,
                                                     float* __restrict__ out) {
  int tid = blockIdx.x * 256 + threadIdx.x;
  int f4i = tid & 15;
  int n = (tid >> 4) & 8191;
  int b = tid >> 17;
  const float* lse = (const float*)((const char*)ws + WS_LSE_B);
  const float* bo  = (const float*)((const char*)ws + WS_BO_B);
  float l[8];
  #pragma unroll
  for (int hh = 0; hh < 8; ++hh) l[hh] = lse[(((size_t)hh * BATCH + b) << 13) + n];
  float m = l[0];
  #pragma unroll
  for (int hh = 1; hh < 8; ++hh) m = fmaxf(m, l[hh]);
  float w[8]; float sum = 0.0f;
  #pragma unroll
  for (int hh = 0; hh < 8; ++hh) { w[hh] = __expf(l[hh] - m); sum += w[hh]; }
  float inv = 1.0f / sum;
  float4 a; a.x = a.y = a.z = a.w = 0.0f;
  #pragma unroll
  for (int hh = 0; hh < 8; ++hh) {
    const float4* p = (const float4*)(bo + ((((size_t)hh * BATCH + b) << 13) + n) * 64) + f4i;
    float4 v = *p;
    float ww = w[hh] * inv;
    a.x = fmaf(ww, v.x, a.x); a.y = fmaf(ww, v.y, a.y);
    a.z = fmaf(ww, v.z, a.z); a.w = fmaf(ww, v.w, a.w);
  }
  ((float4*)out)[tid] = a;
}

// ---------------- launch ----------------
extern "C" void kernel_launch(void* const* d_in, const int* in_sizes, int n_in,
                              void* d_out, int out_size, void* d_ws, size_t ws_size,
                              hipStream_t stream) {
  const float* q = (const float*)d_in[0];
  const float* k = (const float*)d_in[1];
  const float* v = (const float*)d_in[2];
  float* out = (float*)d_out;
  float* ws = (float*)d_ws;

  smyrf_rng<<<1, 256, 0, stream>>>(ws);
  smyrf_norms<<<256, 256, 0, stream>>>(q, k, ws);
  smyrf_keys<<<256, 256, 0, stream>>>(q, k, ws);
  smyrf_sort<<<64, 1024, 0, stream>>>(ws);
  smyrf_attn_mfma<<<NH * BATCH * NCLU, 256, 0, stream>>>(q, k, v, ws);
  smyrf_combine<<<2048, 256, 0, stream>>>(ws, out);
}

// Round 6
// 189.079 us; speedup vs baseline: 5.9119x; 1.4603x over previous
//
#include <hip/hip_runtime.h>
#include <stdint.h>

typedef unsigned int u32;
typedef unsigned long long u64;

// ---------------- problem constants ----------------
#define BATCH 4
#define NSEQ  8192
#define DIM   64
#define NH    8
#define CSZ   128
#define NCLU  64

// ---------------- workspace layout ----------------
#define WS_ALPHA   0
#define WS_BETA    528
#define WS_MAXB    536
#define WS_QN      1024
#define WS_KEYS_B  266240
#define WS_LSE_B   2363392
#define WS_BO_B    3411968
// total = 70,520,832 bytes

typedef short bf16x8 __attribute__((ext_vector_type(8)));
typedef float f32x4 __attribute__((ext_vector_type(4)));
#define MFMA16(a, b, c) __builtin_amdgcn_mfma_f32_16x16x32_bf16(a, b, c, 0, 0, 0)

// ---------------- Threefry-2x32 (JAX) ----------------
__device__ __forceinline__ void tf2x32(u32 k0, u32 k1, u32 x0, u32 x1, u32& o0, u32& o1) {
  u32 ks2 = k0 ^ k1 ^ 0x1BD11BDAu;
  x0 += k0; x1 += k1;
#define TF_RND(r) { x0 += x1; x1 = (x1 << (r)) | (x1 >> (32 - (r))); x1 ^= x0; }
  TF_RND(13) TF_RND(15) TF_RND(26) TF_RND(6)
  x0 += k1; x1 += ks2 + 1u;
  TF_RND(17) TF_RND(29) TF_RND(16) TF_RND(24)
  x0 += ks2; x1 += k0 + 2u;
  TF_RND(13) TF_RND(15) TF_RND(26) TF_RND(6)
  x0 += k0; x1 += k1 + 3u;
  TF_RND(17) TF_RND(29) TF_RND(16) TF_RND(24)
  x0 += k1; x1 += ks2 + 4u;
  TF_RND(13) TF_RND(15) TF_RND(26) TF_RND(6)
  x0 += ks2; x1 += k0 + 5u;
#undef TF_RND
  o0 = x0; o1 = x1;
}

__device__ __forceinline__ float bits01(u32 b) {
  return __uint_as_float((b >> 9) | 0x3f800000u) - 1.0f;
}

__device__ __forceinline__ float xla_erfinv(float x) {
  float x2 = __fmul_rn(x, x);
  float w = (float)(-log1p(-(double)x2));
  float p;
  if (w < 5.0f) {
    float ww = __fsub_rn(w, 2.5f);
    p = 2.81022636e-08f;
    p = __fadd_rn(3.43273939e-07f, __fmul_rn(p, ww));
    p = __fadd_rn(-3.5233877e-06f, __fmul_rn(p, ww));
    p = __fadd_rn(-4.39150654e-06f, __fmul_rn(p, ww));
    p = __fadd_rn(0.00021858087f, __fmul_rn(p, ww));
    p = __fadd_rn(-0.00125372503f, __fmul_rn(p, ww));
    p = __fadd_rn(-0.00417768164f, __fmul_rn(p, ww));
    p = __fadd_rn(0.246640727f, __fmul_rn(p, ww));
    p = __fadd_rn(1.50140941f, __fmul_rn(p, ww));
  } else {
    float ww = __fsub_rn(__fsqrt_rn(w), 3.0f);
    p = -0.000200214257f;
    p = __fadd_rn(0.000100950558f, __fmul_rn(p, ww));
    p = __fadd_rn(0.00134934322f, __fmul_rn(p, ww));
    p = __fadd_rn(-0.00367342844f, __fmul_rn(p, ww));
    p = __fadd_rn(0.00573950773f, __fmul_rn(p, ww));
    p = __fadd_rn(-0.0076224613f, __fmul_rn(p, ww));
    p = __fadd_rn(0.00943887047f, __fmul_rn(p, ww));
    p = __fadd_rn(1.00167406f, __fmul_rn(p, ww));
    p = __fadd_rn(2.83297682f, __fmul_rn(p, ww));
  }
  return __fmul_rn(p, x);
}

// ---------------- k_rng ----------------
__global__ __launch_bounds__(256) void smyrf_rng(float* ws) {
  int t = threadIdx.x;
  float* alpha = ws + WS_ALPHA;
  float* beta  = ws + WS_BETA;
  u32*   maxb  = (u32*)(ws + WS_MAXB);
  if (t < 8) maxb[t] = 0u;
  u32 ka0, ka1, kb0, kb1;
  tf2x32(0u, 42u, 0u, 0u, ka0, ka1);
  tf2x32(0u, 42u, 0u, 1u, kb0, kb1);
  const float LO = __uint_as_float(0xBF7FFFFFu);
  const float SQ2 = 1.4142135623730951f;
  for (int i = t; i < 528; i += 256) {
    u32 o0, o1; tf2x32(ka0, ka1, 0u, (u32)i, o0, o1);
    u32 bits = o0 ^ o1;
    float u = __fadd_rn(__fmul_rn(bits01(bits), 2.0f), LO);
    alpha[i] = __fmul_rn(SQ2, xla_erfinv(u));
  }
  if (t < 8) {
    u32 o0, o1; tf2x32(kb0, kb1, 0u, (u32)t, o0, o1);
    beta[t] = bits01(o0 ^ o1);
  }
}

// ---------------- k_norms (R1 fix: block-reduced atomicMax) ----------------
__global__ __launch_bounds__(256) void smyrf_norms(const float* __restrict__ Q,
                                                   const float* __restrict__ Kk,
                                                   float* ws) {
  int tid = blockIdx.x * 256 + threadIdx.x;
  int tensor = tid >> 15;
  const float* x = (tensor ? Kk : Q) + (size_t)(tid & 32767) * DIM;
  const float4* x4 = (const float4*)x;
  double s = 0.0;
  #pragma unroll
  for (int i = 0; i < 16; ++i) {
    float4 v = x4[i];
    s += (double)v.x * v.x + (double)v.y * v.y + (double)v.z * v.z + (double)v.w * v.w;
  }
  float qn = (float)sqrt(s);
  (ws + WS_QN)[tid] = qn;
  float wmax = qn;
  #pragma unroll
  for (int off = 1; off < 64; off <<= 1) wmax = fmaxf(wmax, __shfl_xor(wmax, off));
  __shared__ float red[4];
  int wave = threadIdx.x >> 6;
  if ((threadIdx.x & 63) == 0) red[wave] = wmax;
  __syncthreads();
  if (threadIdx.x == 0) {
    float m = fmaxf(fmaxf(red[0], red[1]), fmaxf(red[2], red[3]));
    int b = (tid >> 13) & 3;
    atomicMax((u32*)(ws + WS_MAXB) + tensor * 4 + b, __float_as_uint(m));
  }
}

// ---------------- k_keys ----------------
__global__ __launch_bounds__(256) void smyrf_keys(const float* __restrict__ Q,
                                                  const float* __restrict__ Kk,
                                                  float* ws) {
  int tid = blockIdx.x * 256 + threadIdx.x;
  int tensor = tid >> 15;
  int b = (tid >> 13) & 3;
  int n = tid & 8191;
  const float* x = (tensor ? Kk : Q) + (size_t)(tid & 32767) * DIM;
  float r[64];
  const float4* x4 = (const float4*)x;
  #pragma unroll
  for (int i = 0; i < 16; ++i) {
    float4 v = x4[i];
    r[4 * i] = v.x; r[4 * i + 1] = v.y; r[4 * i + 2] = v.z; r[4 * i + 3] = v.w;
  }
  const float* alpha = ws + WS_ALPHA;
  const float* beta  = ws + WS_BETA;
  const u32*   maxb  = (const u32*)(ws + WS_MAXB);
  float qn = (ws + WS_QN)[tid];
  float mq = __uint_as_float(maxb[b]);
  float mk = __uint_as_float(maxb[4 + b]);
  float M2 = __fadd_rn(__fmul_rn(mq, mq), __fmul_rn(mk, mk));
  float ex = __fsqrt_rn(fmaxf(__fsub_rn(M2, __fmul_rn(qn, qn)), 0.0f));
  u32* keys = (u32*)((char*)ws + WS_KEYS_B);
  #pragma unroll 1
  for (int hh = 0; hh < NH; ++hh) {
    const float* al = alpha + hh * 66;
    double dot = 0.0;
    #pragma unroll
    for (int d = 0; d < 64; ++d) dot = fma((double)r[d], (double)al[d], dot);
    dot = fma((double)ex, (double)al[64 + tensor], dot);
    float val = __fadd_rn((float)dot, beta[hh]);
    float fb = floorf(val);
    int ib = (fb >= 262143.f) ? 262143 : ((fb <= -262144.f) ? -262144 : (int)fb);
    keys[((size_t)tensor * NH * BATCH + (size_t)hh * BATCH + b) * NSEQ + n] =
        ((u32)(ib + 262144) << 13) | (u32)n;
  }
}

// ---------------- k_sort (R4 rewrite): stable LDS radix, dynamic pass count ----
// Keys unique: (bucket+262144)<<13 | idx. Rebase digits on per-segment min
// bucket -> range ~160 in practice => 1 pass of 8 bits (worst case 3 passes,
// still exact). Stability: processing order (wave, round, lane) == index order;
// scatter rank = waveoff + earlier-rounds count + ballot-rank.
__global__ __launch_bounds__(1024) void smyrf_sort(float* ws) {
  __shared__ u32 arrA[8192];
  __shared__ u32 arrB[8192];
  __shared__ u32 hist[16][256];
  __shared__ u32 scanbuf[256];
  __shared__ u32 wmn[16], wmx[16], mnmx[2];
  u32* base = (u32*)((char*)ws + WS_KEYS_B) + (size_t)blockIdx.x * 8192;
  int t = threadIdx.x;
  int w = t >> 6, l = t & 63;
  u64 ltmask = (1ull << l) - 1ull;

  // load + min/max bucket
  u32 mn = 0xFFFFFFFFu, mx = 0u;
  for (int i = t; i < 8192; i += 1024) {
    u32 k = base[i];
    arrA[i] = k;
    u32 bk = k >> 13;
    mn = min(mn, bk); mx = max(mx, bk);
  }
  #pragma unroll
  for (int off = 1; off < 64; off <<= 1) {
    mn = min(mn, (u32)__shfl_xor((int)mn, off));
    mx = max(mx, (u32)__shfl_xor((int)mx, off));
  }
  if (l == 0) { wmn[w] = mn; wmx[w] = mx; }
  __syncthreads();
  if (t == 0) {
    u32 a = wmn[0], bb = wmx[0];
    #pragma unroll
    for (int i = 1; i < 16; ++i) { a = min(a, wmn[i]); bb = max(bb, wmx[i]); }
    mnmx[0] = a; mnmx[1] = bb;
  }
  __syncthreads();
  u32 minb = mnmx[0];
  u32 range = mnmx[1] - minb;
  int npass = (range < 256u) ? 1 : ((range < 65536u) ? 2 : 3);

  u32* src = arrA;
  u32* dst = arrB;
  for (int p = 0; p < npass; ++p) {
    int sh = 8 * p;
    // zero hist
    for (int i = t; i < 16 * 256; i += 1024) ((u32*)hist)[i] = 0u;
    __syncthreads();
    // per-wave histogram (wave w owns elements [512w, 512w+512))
    #pragma unroll 1
    for (int r = 0; r < 8; ++r) {
      u32 key = src[w * 512 + r * 64 + l];
      u32 d = (((key >> 13) - minb) >> sh) & 255u;
      atomicAdd(&hist[w][d], 1u);
    }
    __syncthreads();
    // scan: hist[w][d] -> global stable base for (wave w, digit d)
    u32 mytot = 0;
    if (t < 256) {
      u32 run = 0;
      #pragma unroll
      for (int ww = 0; ww < 16; ++ww) { u32 c = hist[ww][t]; hist[ww][t] = run; run += c; }
      mytot = run;
      scanbuf[t] = run;
    }
    __syncthreads();
    for (int s = 1; s < 256; s <<= 1) {
      u32 v = 0;
      if (t < 256 && t >= s) v = scanbuf[t - s];
      __syncthreads();
      if (t < 256) scanbuf[t] += v;
      __syncthreads();
    }
    if (t < 256) {
      u32 off = scanbuf[t] - mytot;   // exclusive digit offset
      #pragma unroll
      for (int ww = 0; ww < 16; ++ww) hist[ww][t] += off;
    }
    __syncthreads();
    // stable scatter in (w, r, l) order
    #pragma unroll 1
    for (int r = 0; r < 8; ++r) {
      u32 key = src[w * 512 + r * 64 + l];
      u32 d = (((key >> 13) - minb) >> sh) & 255u;
      // peers = lanes in this wave with same digit (bitwise ballot match)
      u64 peers = ~0ull;
      #pragma unroll
      for (int bit = 0; bit < 8; ++bit) {
        bool myb = (d >> bit) & 1u;
        u64 vote = __ballot(myb);
        peers &= myb ? vote : ~vote;
      }
      u32 rank = (u32)__popcll(peers & ltmask);
      u32 cnt = (u32)__popcll(peers);
      int leaderLane = (int)__ffsll((long long)peers) - 1;
      u32 old = 0;
      if (l == leaderLane) old = atomicAdd(&hist[w][d], cnt);
      old = (u32)__shfl((int)old, leaderLane);
      dst[old + rank] = key;
    }
    __syncthreads();
    u32* tmp = src; src = dst; dst = tmp;
  }
  for (int i = t; i < 8192; i += 1024) base[i] = src[i];
}

// ---------------- k_attn (R2): MFMA split-bf16 ----------------
__device__ __forceinline__ ushort f2bf(float x) {
  u32 xb = __float_as_uint(x);
  return (ushort)((xb + 0x7FFFu + ((xb >> 16) & 1u)) >> 16);
}
__device__ __forceinline__ float bf2f(ushort h) { return __uint_as_float(((u32)h) << 16); }
__device__ __forceinline__ int swz(int row, int kb) { return row * 128 + (kb ^ ((row & 7) << 4)); }

__global__ __launch_bounds__(256) void smyrf_attn_mfma(const float* __restrict__ Q,
                                                       const float* __restrict__ K,
                                                       const float* __restrict__ V,
                                                       float* __restrict__ ws) {
  __shared__ uint4 smem_u4[4096];   // 64 KB
  char* sm = (char*)smem_u4;
  int id = blockIdx.x;
  int c = id & 63, b = (id >> 6) & 3, h = id >> 8;
  int t = threadIdx.x;
  int lane = t & 63, w = t >> 6;
  int cl = lane & 15, ag = lane >> 4;

  const u32* keys = (const u32*)((const char*)ws + WS_KEYS_B);
  const u32* qkp = keys + ((size_t)h * BATCH + b) * NSEQ + c * CSZ;
  const u32* kkp = keys + (size_t)NH * BATCH * NSEQ + ((size_t)h * BATCH + b) * NSEQ + c * CSZ;
  const float* Qb = Q + (size_t)b * NSEQ * DIM;
  const float* Kb = K + (size_t)b * NSEQ * DIM;
  const float* Vb = V + (size_t)b * NSEQ * DIM;

  // ---- stage Q,K as hi/lo bf16 planes ----
  {
    int row = t & 127;
    int tensor = t >> 7;                   // 0=Q, 1=K
    int tok = (int)((tensor ? kkp[row] : qkp[row]) & 8191);
    const float* src = (tensor ? Kb : Qb) + (size_t)tok * DIM;
    char* hb = sm + tensor * 32768;
    char* lb = hb + 16384;
    int sw = (row & 7) << 4;
    #pragma unroll
    for (int c8 = 0; c8 < 8; ++c8) {
      float4 a = *(const float4*)(src + c8 * 8);
      float4 cc = *(const float4*)(src + c8 * 8 + 4);
      float v[8] = {a.x, a.y, a.z, a.w, cc.x, cc.y, cc.z, cc.w};
      ushort hh[8], ll[8];
      #pragma unroll
      for (int j = 0; j < 8; ++j) { hh[j] = f2bf(v[j]); ll[j] = f2bf(v[j] - bf2f(hh[j])); }
      uint4 hv, lv;
      hv.x = (u32)hh[0] | ((u32)hh[1] << 16); hv.y = (u32)hh[2] | ((u32)hh[3] << 16);
      hv.z = (u32)hh[4] | ((u32)hh[5] << 16); hv.w = (u32)hh[6] | ((u32)hh[7] << 16);
      lv.x = (u32)ll[0] | ((u32)ll[1] << 16); lv.y = (u32)ll[2] | ((u32)ll[3] << 16);
      lv.z = (u32)ll[4] | ((u32)ll[5] << 16); lv.w = (u32)ll[6] | ((u32)ll[7] << 16);
      int off = row * 128 + ((c8 * 16) ^ sw);
      *(uint4*)&hb[off] = hv;
      *(uint4*)&lb[off] = lv;
    }
  }
  __syncthreads();

  // ---- QK^T: S[q][k], wave w owns q in [32w,32w+32) ----
  f32x4 S[2][8];
  #pragma unroll
  for (int m = 0; m < 2; ++m)
    #pragma unroll
    for (int n = 0; n < 8; ++n) S[m][n] = (f32x4){0.f, 0.f, 0.f, 0.f};
  {
    const char* Qhi = sm, *Qlo = sm + 16384, *Khi = sm + 32768, *Klo = sm + 49152;
    #pragma unroll
    for (int kk_ = 0; kk_ < 2; ++kk_) {
      int kb = kk_ * 64 + ag * 16;
      bf16x8 qh0 = *(const bf16x8*)&Qhi[swz(w * 32 + cl, kb)];
      bf16x8 qh1 = *(const bf16x8*)&Qhi[swz(w * 32 + 16 + cl, kb)];
      bf16x8 ql0 = *(const bf16x8*)&Qlo[swz(w * 32 + cl, kb)];
      bf16x8 ql1 = *(const bf16x8*)&Qlo[swz(w * 32 + 16 + cl, kb)];
      #pragma unroll
      for (int n = 0; n < 8; ++n) {
        int o = swz(n * 16 + cl, kb);
        bf16x8 kh = *(const bf16x8*)&Khi[o];
        bf16x8 kl = *(const bf16x8*)&Klo[o];
        S[0][n] = MFMA16(qh0, kh, S[0][n]);
        S[1][n] = MFMA16(qh1, kh, S[1][n]);
        S[0][n] = MFMA16(qh0, kl, S[0][n]);
        S[1][n] = MFMA16(qh1, kl, S[1][n]);
        S[0][n] = MFMA16(ql0, kh, S[0][n]);
        S[1][n] = MFMA16(ql1, kh, S[1][n]);
      }
    }
  }

  // ---- softmax ----
  float inv_[2][4];
  float* lse = (float*)((char*)ws + WS_LSE_B);
  #pragma unroll
  for (int m = 0; m < 2; ++m)
    #pragma unroll
    for (int r = 0; r < 4; ++r) {
      float mx = S[m][0][r];
      #pragma unroll
      for (int n = 1; n < 8; ++n) mx = fmaxf(mx, S[m][n][r]);
      mx = fmaxf(mx, __shfl_xor(mx, 1));
      mx = fmaxf(mx, __shfl_xor(mx, 2));
      mx = fmaxf(mx, __shfl_xor(mx, 4));
      mx = fmaxf(mx, __shfl_xor(mx, 8));
      float sum = 0.f;
      #pragma unroll
      for (int n = 0; n < 8; ++n) { float e = __expf(S[m][n][r] - mx); S[m][n][r] = e; sum += e; }
      sum += __shfl_xor(sum, 1);
      sum += __shfl_xor(sum, 2);
      sum += __shfl_xor(sum, 4);
      sum += __shfl_xor(sum, 8);
      inv_[m][r] = 1.0f / sum;
      if (cl == 0) {
        int q = w * 32 + m * 16 + ag * 4 + r;
        lse[(((size_t)h * BATCH + b) << 13) + (qkp[q] & 8191)] = mx + __logf(sum);
      }
    }

  // ---- PV in two k-halves ----
  f32x4 O[4][2];
  #pragma unroll
  for (int mt = 0; mt < 4; ++mt)
    #pragma unroll
    for (int nt = 0; nt < 2; ++nt) O[mt][nt] = (f32x4){0.f, 0.f, 0.f, 0.f};

  #pragma unroll
  for (int half = 0; half < 2; ++half) {
    __syncthreads();
    #pragma unroll
    for (int m = 0; m < 2; ++m)
      #pragma unroll
      for (int r = 0; r < 4; ++r) {
        int row = w * 32 + m * 16 + ag * 4 + r;
        int sw2 = (row & 7) << 4;
        float iv = inv_[m][r];
        #pragma unroll
        for (int n4 = 0; n4 < 4; ++n4) {
          float p = S[m][half * 4 + n4][r] * iv;
          ushort ph = f2bf(p);
          ushort pl = f2bf(p - bf2f(ph));
          int off = row * 128 + ((2 * (n4 * 16 + cl)) ^ sw2);
          *(ushort*)&sm[off] = ph;
          *(ushort*)&sm[16384 + off] = pl;
        }
      }
    if (half == 0) {
      int tok = t >> 1, dh = (t & 1) * 32;
      const float* vs = Vb + (size_t)(kkp[tok] & 8191) * DIM + dh;
      #pragma unroll
      for (int c4 = 0; c4 < 8; ++c4) {
        float4 a = *(const float4*)(vs + c4 * 4);
        float vv[4] = {a.x, a.y, a.z, a.w};
        #pragma unroll
        for (int j = 0; j < 4; ++j) {
          int dv = dh + c4 * 4 + j;
          ushort vh = f2bf(vv[j]);
          ushort vl = f2bf(vv[j] - bf2f(vh));
          int off = dv * 256 + ((2 * tok) ^ ((dv & 7) << 5));
          *(ushort*)&sm[32768 + off] = vh;
          *(ushort*)&sm[49152 + off] = vl;
        }
      }
    }
    __syncthreads();
    #pragma unroll
    for (int k2 = 0; k2 < 2; ++k2) {
      int kbP = k2 * 64 + ag * 16;
      int kbV = half * 128 + k2 * 64 + ag * 16;
      bf16x8 p0h = *(const bf16x8*)&sm[swz(w * 32 + cl, kbP)];
      bf16x8 p0l = *(const bf16x8*)&sm[16384 + swz(w * 32 + cl, kbP)];
      bf16x8 p1h = *(const bf16x8*)&sm[swz(w * 32 + 16 + cl, kbP)];
      bf16x8 p1l = *(const bf16x8*)&sm[16384 + swz(w * 32 + 16 + cl, kbP)];
      #pragma unroll
      for (int mt = 0; mt < 4; ++mt) {
        int dv = mt * 16 + cl;
        int off = dv * 256 + (kbV ^ ((dv & 7) << 5));
        bf16x8 vh = *(const bf16x8*)&sm[32768 + off];
        bf16x8 vl = *(const bf16x8*)&sm[49152 + off];
        O[mt][0] = MFMA16(vh, p0h, O[mt][0]);
        O[mt][0] = MFMA16(vh, p0l, O[mt][0]);
        O[mt][0] = MFMA16(vl, p0h, O[mt][0]);
        O[mt][1] = MFMA16(vh, p1h, O[mt][1]);
        O[mt][1] = MFMA16(vh, p1l, O[mt][1]);
        O[mt][1] = MFMA16(vl, p1h, O[mt][1]);
      }
    }
  }

  // ---- epilogue ----
  float* bo = (float*)((char*)ws + WS_BO_B);
  #pragma unroll
  for (int nt = 0; nt < 2; ++nt) {
    int q = w * 32 + nt * 16 + cl;
    int tok = (int)(qkp[q] & 8191);
    float* orow = bo + ((((size_t)h * BATCH + b) << 13) + tok) * 64;
    #pragma unroll
    for (int mt = 0; mt < 4; ++mt) {
      *(f32x4*)&orow[mt * 16 + ag * 4] = O[mt][nt];
    }
  }
}

// ---------------- k_combine ----------------
__global__ __launch_bounds__(256) void smyrf_combine(const float* __restrict__ ws,
                                                     float* __restrict__ out) {
  int tid = blockIdx.x * 256 + threadIdx.x;
  int f4i = tid & 15;
  int n = (tid >> 4) & 8191;
  int b = tid >> 17;
  const float* lse = (const float*)((const char*)ws + WS_LSE_B);
  const float* bo  = (const float*)((const char*)ws + WS_BO_B);
  float l[8];
  #pragma unroll
  for (int hh = 0; hh < 8; ++hh) l[hh] = lse[(((size_t)hh * BATCH + b) << 13) + n];
  float m = l[0];
  #pragma unroll
  for (int hh = 1; hh < 8; ++hh) m = fmaxf(m, l[hh]);
  float w[8]; float sum = 0.0f;
  #pragma unroll
  for (int hh = 0; hh < 8; ++hh) { w[hh] = __expf(l[hh] - m); sum += w[hh]; }
  float inv = 1.0f / sum;
  float4 a; a.x = a.y = a.z = a.w = 0.0f;
  #pragma unroll
  for (int hh = 0; hh < 8; ++hh) {
    const float4* p = (const float4*)(bo + ((((size_t)hh * BATCH + b) << 13) + n) * 64) + f4i;
    float4 v = *p;
    float ww = w[hh] * inv;
    a.x = fmaf(ww, v.x, a.x); a.y = fmaf(ww, v.y, a.y);
    a.z = fmaf(ww, v.z, a.z); a.w = fmaf(ww, v.w, a.w);
  }
  ((float4*)out)[tid] = a;
}

// ---------------- launch ----------------
extern "C" void kernel_launch(void* const* d_in, const int* in_sizes, int n_in,
                              void* d_out, int out_size, void* d_ws, size_t ws_size,
                              hipStream_t stream) {
  const float* q = (const float*)d_in[0];
  const float* k = (const float*)d_in[1];
  const float* v = (const float*)d_in[2];
  float* out = (float*)d_out;
  float* ws = (float*)d_ws;

  smyrf_rng<<<1, 256, 0, stream>>>(ws);
  smyrf_norms<<<256, 256, 0, stream>>>(q, k, ws);
  smyrf_keys<<<256, 256, 0, stream>>>(q, k, ws);
  smyrf_sort<<<64, 1024, 0, stream>>>(ws);
  smyrf_attn_mfma<<<NH * BATCH * NCLU, 256, 0, stream>>>(q, k, v, ws);
  smyrf_combine<<<2048, 256, 0, stream>>>(ws, out);
}

// Round 8
// 184.543 us; speedup vs baseline: 6.0572x; 1.0246x over previous
//
#include <hip/hip_runtime.h>
#include <stdint.h>

typedef unsigned int u32;
typedef unsigned long long u64;

// ---------------- problem constants ----------------
#define BATCH 4
#define NSEQ  8192
#define DIM   64
#define NH    8
#define CSZ   128
#define NCLU  64

// ---------------- workspace layout ----------------
#define WS_ALPHA   0
#define WS_BETA    528
#define WS_MAXB    536
#define WS_QN      1024
#define WS_KEYS_B  266240
#define WS_LSE_B   2363392
#define WS_BO_B    3411968      // bf16 [8][4][8192][64] = 32 MiB
// total = 36,966,400 bytes

typedef short bf16x8 __attribute__((ext_vector_type(8)));
typedef float f32x4 __attribute__((ext_vector_type(4)));
#define MFMA16(a, b, c) __builtin_amdgcn_mfma_f32_16x16x32_bf16(a, b, c, 0, 0, 0)

// packed f32->bf16 RNE (bit-identical to manual round-to-nearest-even split)
__device__ __forceinline__ u32 cvtpk(float lo, float hi) {
  u32 d;
  asm("v_cvt_pk_bf16_f32 %0, %1, %2" : "=v"(d) : "v"(lo), "v"(hi));
  return d;
}
__device__ __forceinline__ float uaf(u32 x) { return __uint_as_float(x); }

// ---------------- Threefry-2x32 (JAX) ----------------
__device__ __forceinline__ void tf2x32(u32 k0, u32 k1, u32 x0, u32 x1, u32& o0, u32& o1) {
  u32 ks2 = k0 ^ k1 ^ 0x1BD11BDAu;
  x0 += k0; x1 += k1;
#define TF_RND(r) { x0 += x1; x1 = (x1 << (r)) | (x1 >> (32 - (r))); x1 ^= x0; }
  TF_RND(13) TF_RND(15) TF_RND(26) TF_RND(6)
  x0 += k1; x1 += ks2 + 1u;
  TF_RND(17) TF_RND(29) TF_RND(16) TF_RND(24)
  x0 += ks2; x1 += k0 + 2u;
  TF_RND(13) TF_RND(15) TF_RND(26) TF_RND(6)
  x0 += k0; x1 += k1 + 3u;
  TF_RND(17) TF_RND(29) TF_RND(16) TF_RND(24)
  x0 += k1; x1 += ks2 + 4u;
  TF_RND(13) TF_RND(15) TF_RND(26) TF_RND(6)
  x0 += ks2; x1 += k0 + 5u;
#undef TF_RND
  o0 = x0; o1 = x1;
}

__device__ __forceinline__ float bits01(u32 b) {
  return __uint_as_float((b >> 9) | 0x3f800000u) - 1.0f;
}

__device__ __forceinline__ float xla_erfinv(float x) {
  float x2 = __fmul_rn(x, x);
  float w = (float)(-log1p(-(double)x2));
  float p;
  if (w < 5.0f) {
    float ww = __fsub_rn(w, 2.5f);
    p = 2.81022636e-08f;
    p = __fadd_rn(3.43273939e-07f, __fmul_rn(p, ww));
    p = __fadd_rn(-3.5233877e-06f, __fmul_rn(p, ww));
    p = __fadd_rn(-4.39150654e-06f, __fmul_rn(p, ww));
    p = __fadd_rn(0.00021858087f, __fmul_rn(p, ww));
    p = __fadd_rn(-0.00125372503f, __fmul_rn(p, ww));
    p = __fadd_rn(-0.00417768164f, __fmul_rn(p, ww));
    p = __fadd_rn(0.246640727f, __fmul_rn(p, ww));
    p = __fadd_rn(1.50140941f, __fmul_rn(p, ww));
  } else {
    float ww = __fsub_rn(__fsqrt_rn(w), 3.0f);
    p = -0.000200214257f;
    p = __fadd_rn(0.000100950558f, __fmul_rn(p, ww));
    p = __fadd_rn(0.00134934322f, __fmul_rn(p, ww));
    p = __fadd_rn(-0.00367342844f, __fmul_rn(p, ww));
    p = __fadd_rn(0.00573950773f, __fmul_rn(p, ww));
    p = __fadd_rn(-0.0076224613f, __fmul_rn(p, ww));
    p = __fadd_rn(0.00943887047f, __fmul_rn(p, ww));
    p = __fadd_rn(1.00167406f, __fmul_rn(p, ww));
    p = __fadd_rn(2.83297682f, __fmul_rn(p, ww));
  }
  return __fmul_rn(p, x);
}

// ---------------- k_rng ----------------
__global__ __launch_bounds__(256) void smyrf_rng(float* ws) {
  int t = threadIdx.x;
  float* alpha = ws + WS_ALPHA;
  float* beta  = ws + WS_BETA;
  u32*   maxb  = (u32*)(ws + WS_MAXB);
  if (t < 8) maxb[t] = 0u;
  u32 ka0, ka1, kb0, kb1;
  tf2x32(0u, 42u, 0u, 0u, ka0, ka1);
  tf2x32(0u, 42u, 0u, 1u, kb0, kb1);
  const float LO = __uint_as_float(0xBF7FFFFFu);
  const float SQ2 = 1.4142135623730951f;
  for (int i = t; i < 528; i += 256) {
    u32 o0, o1; tf2x32(ka0, ka1, 0u, (u32)i, o0, o1);
    u32 bits = o0 ^ o1;
    float u = __fadd_rn(__fmul_rn(bits01(bits), 2.0f), LO);
    alpha[i] = __fmul_rn(SQ2, xla_erfinv(u));
  }
  if (t < 8) {
    u32 o0, o1; tf2x32(kb0, kb1, 0u, (u32)t, o0, o1);
    beta[t] = bits01(o0 ^ o1);
  }
}

// ---------------- k_norms ----------------
__global__ __launch_bounds__(256) void smyrf_norms(const float* __restrict__ Q,
                                                   const float* __restrict__ Kk,
                                                   float* ws) {
  int tid = blockIdx.x * 256 + threadIdx.x;
  int tensor = tid >> 15;
  const float* x = (tensor ? Kk : Q) + (size_t)(tid & 32767) * DIM;
  const float4* x4 = (const float4*)x;
  double s = 0.0;
  #pragma unroll
  for (int i = 0; i < 16; ++i) {
    float4 v = x4[i];
    s += (double)v.x * v.x + (double)v.y * v.y + (double)v.z * v.z + (double)v.w * v.w;
  }
  float qn = (float)sqrt(s);
  (ws + WS_QN)[tid] = qn;
  float wmax = qn;
  #pragma unroll
  for (int off = 1; off < 64; off <<= 1) wmax = fmaxf(wmax, __shfl_xor(wmax, off));
  __shared__ float red[4];
  int wave = threadIdx.x >> 6;
  if ((threadIdx.x & 63) == 0) red[wave] = wmax;
  __syncthreads();
  if (threadIdx.x == 0) {
    float m = fmaxf(fmaxf(red[0], red[1]), fmaxf(red[2], red[3]));
    int b = (tid >> 13) & 3;
    atomicMax((u32*)(ws + WS_MAXB) + tensor * 4 + b, __float_as_uint(m));
  }
}

// ---------------- k_keys ----------------
__global__ __launch_bounds__(256) void smyrf_keys(const float* __restrict__ Q,
                                                  const float* __restrict__ Kk,
                                                  float* ws) {
  int tid = blockIdx.x * 256 + threadIdx.x;
  int tensor = tid >> 15;
  int b = (tid >> 13) & 3;
  int n = tid & 8191;
  const float* x = (tensor ? Kk : Q) + (size_t)(tid & 32767) * DIM;
  float r[64];
  const float4* x4 = (const float4*)x;
  #pragma unroll
  for (int i = 0; i < 16; ++i) {
    float4 v = x4[i];
    r[4 * i] = v.x; r[4 * i + 1] = v.y; r[4 * i + 2] = v.z; r[4 * i + 3] = v.w;
  }
  const float* alpha = ws + WS_ALPHA;
  const float* beta  = ws + WS_BETA;
  const u32*   maxb  = (const u32*)(ws + WS_MAXB);
  float qn = (ws + WS_QN)[tid];
  float mq = __uint_as_float(maxb[b]);
  float mk = __uint_as_float(maxb[4 + b]);
  float M2 = __fadd_rn(__fmul_rn(mq, mq), __fmul_rn(mk, mk));
  float ex = __fsqrt_rn(fmaxf(__fsub_rn(M2, __fmul_rn(qn, qn)), 0.0f));
  u32* keys = (u32*)((char*)ws + WS_KEYS_B);
  #pragma unroll 1
  for (int hh = 0; hh < NH; ++hh) {
    const float* al = alpha + hh * 66;
    double dot = 0.0;
    #pragma unroll
    for (int d = 0; d < 64; ++d) dot = fma((double)r[d], (double)al[d], dot);
    dot = fma((double)ex, (double)al[64 + tensor], dot);
    float val = __fadd_rn((float)dot, beta[hh]);
    float fb = floorf(val);
    int ib = (fb >= 262143.f) ? 262143 : ((fb <= -262144.f) ? -262144 : (int)fb);
    keys[((size_t)tensor * NH * BATCH + (size_t)hh * BATCH + b) * NSEQ + n] =
        ((u32)(ib + 262144) << 13) | (u32)n;
  }
}

// ---------------- k_sort (R4): stable LDS radix, dynamic pass count ----------------
__global__ __launch_bounds__(1024) void smyrf_sort(float* ws) {
  __shared__ u32 arrA[8192];
  __shared__ u32 arrB[8192];
  __shared__ u32 hist[16][256];
  __shared__ u32 scanbuf[256];
  __shared__ u32 wmn[16], wmx[16], mnmx[2];
  u32* base = (u32*)((char*)ws + WS_KEYS_B) + (size_t)blockIdx.x * 8192;
  int t = threadIdx.x;
  int w = t >> 6, l = t & 63;
  u64 ltmask = (1ull << l) - 1ull;

  u32 mn = 0xFFFFFFFFu, mx = 0u;
  for (int i = t; i < 8192; i += 1024) {
    u32 k = base[i];
    arrA[i] = k;
    u32 bk = k >> 13;
    mn = min(mn, bk); mx = max(mx, bk);
  }
  #pragma unroll
  for (int off = 1; off < 64; off <<= 1) {
    mn = min(mn, (u32)__shfl_xor((int)mn, off));
    mx = max(mx, (u32)__shfl_xor((int)mx, off));
  }
  if (l == 0) { wmn[w] = mn; wmx[w] = mx; }
  __syncthreads();
  if (t == 0) {
    u32 a = wmn[0], bb = wmx[0];
    #pragma unroll
    for (int i = 1; i < 16; ++i) { a = min(a, wmn[i]); bb = max(bb, wmx[i]); }
    mnmx[0] = a; mnmx[1] = bb;
  }
  __syncthreads();
  u32 minb = mnmx[0];
  u32 range = mnmx[1] - minb;
  int npass = (range < 256u) ? 1 : ((range < 65536u) ? 2 : 3);

  u32* src = arrA;
  u32* dst = arrB;
  for (int p = 0; p < npass; ++p) {
    int sh = 8 * p;
    for (int i = t; i < 16 * 256; i += 1024) ((u32*)hist)[i] = 0u;
    __syncthreads();
    #pragma unroll 1
    for (int r = 0; r < 8; ++r) {
      u32 key = src[w * 512 + r * 64 + l];
      u32 d = (((key >> 13) - minb) >> sh) & 255u;
      atomicAdd(&hist[w][d], 1u);
    }
    __syncthreads();
    u32 mytot = 0;
    if (t < 256) {
      u32 run = 0;
      #pragma unroll
      for (int ww = 0; ww < 16; ++ww) { u32 c = hist[ww][t]; hist[ww][t] = run; run += c; }
      mytot = run;
      scanbuf[t] = run;
    }
    __syncthreads();
    for (int s = 1; s < 256; s <<= 1) {
      u32 v = 0;
      if (t < 256 && t >= s) v = scanbuf[t - s];
      __syncthreads();
      if (t < 256) scanbuf[t] += v;
      __syncthreads();
    }
    if (t < 256) {
      u32 off = scanbuf[t] - mytot;
      #pragma unroll
      for (int ww = 0; ww < 16; ++ww) hist[ww][t] += off;
    }
    __syncthreads();
    #pragma unroll 1
    for (int r = 0; r < 8; ++r) {
      u32 key = src[w * 512 + r * 64 + l];
      u32 d = (((key >> 13) - minb) >> sh) & 255u;
      u64 peers = ~0ull;
      #pragma unroll
      for (int bit = 0; bit < 8; ++bit) {
        bool myb = (d >> bit) & 1u;
        u64 vote = __ballot(myb);
        peers &= myb ? vote : ~vote;
      }
      u32 rank = (u32)__popcll(peers & ltmask);
      u32 cnt = (u32)__popcll(peers);
      int leaderLane = (int)__ffsll((long long)peers) - 1;
      u32 old = 0;
      if (l == leaderLane) old = atomicAdd(&hist[w][d], cnt);
      old = (u32)__shfl((int)old, leaderLane);
      dst[old + rank] = key;
    }
    __syncthreads();
    u32* tmp = src; src = dst; dst = tmp;
  }
  for (int i = t; i < 8192; i += 1024) base[i] = src[i];
}

// ---------------- k_attn: MFMA split-bf16; R6: cvt_pk conversions + bf16 bo ----------------
__device__ __forceinline__ int swz(int row, int kb) { return row * 128 + (kb ^ ((row & 7) << 4)); }

__global__ __launch_bounds__(256) void smyrf_attn_mfma(const float* __restrict__ Q,
                                                       const float* __restrict__ K,
                                                       const float* __restrict__ V,
                                                       float* __restrict__ ws) {
  __shared__ uint4 smem_u4[4096];   // 64 KB
  char* sm = (char*)smem_u4;
  int id = blockIdx.x;
  int c = id & 63, b = (id >> 6) & 3, h = id >> 8;
  int t = threadIdx.x;
  int lane = t & 63, w = t >> 6;
  int cl = lane & 15, ag = lane >> 4;

  const u32* keys = (const u32*)((const char*)ws + WS_KEYS_B);
  const u32* qkp = keys + ((size_t)h * BATCH + b) * NSEQ + c * CSZ;
  const u32* kkp = keys + (size_t)NH * BATCH * NSEQ + ((size_t)h * BATCH + b) * NSEQ + c * CSZ;
  const float* Qb = Q + (size_t)b * NSEQ * DIM;
  const float* Kb = K + (size_t)b * NSEQ * DIM;
  const float* Vb = V + (size_t)b * NSEQ * DIM;

  // ---- stage Q,K as hi/lo bf16 planes (cvt_pk pairs) ----
  {
    int row = t & 127;
    int tensor = t >> 7;
    int tok = (int)((tensor ? kkp[row] : qkp[row]) & 8191);
    const float* src = (tensor ? Kb : Qb) + (size_t)tok * DIM;
    char* hb = sm + tensor * 32768;
    char* lb = hb + 16384;
    int sw = (row & 7) << 4;
    #pragma unroll
    for (int c8 = 0; c8 < 8; ++c8) {
      float4 a = *(const float4*)(src + c8 * 8);
      float4 cc = *(const float4*)(src + c8 * 8 + 4);
      float v[8] = {a.x, a.y, a.z, a.w, cc.x, cc.y, cc.z, cc.w};
      uint4 hv, lv;
      u32 hx;
      hx = cvtpk(v[0], v[1]); hv.x = hx;
      lv.x = cvtpk(v[0] - uaf(hx << 16), v[1] - uaf(hx & 0xFFFF0000u));
      hx = cvtpk(v[2], v[3]); hv.y = hx;
      lv.y = cvtpk(v[2] - uaf(hx << 16), v[3] - uaf(hx & 0xFFFF0000u));
      hx = cvtpk(v[4], v[5]); hv.z = hx;
      lv.z = cvtpk(v[4] - uaf(hx << 16), v[5] - uaf(hx & 0xFFFF0000u));
      hx = cvtpk(v[6], v[7]); hv.w = hx;
      lv.w = cvtpk(v[6] - uaf(hx << 16), v[7] - uaf(hx & 0xFFFF0000u));
      int off = row * 128 + ((c8 * 16) ^ sw);
      *(uint4*)&hb[off] = hv;
      *(uint4*)&lb[off] = lv;
    }
  }
  __syncthreads();

  // ---- QK^T ----
  f32x4 S[2][8];
  #pragma unroll
  for (int m = 0; m < 2; ++m)
    #pragma unroll
    for (int n = 0; n < 8; ++n) S[m][n] = (f32x4){0.f, 0.f, 0.f, 0.f};
  {
    const char* Qhi = sm, *Qlo = sm + 16384, *Khi = sm + 32768, *Klo = sm + 49152;
    #pragma unroll
    for (int kk_ = 0; kk_ < 2; ++kk_) {
      int kb = kk_ * 64 + ag * 16;
      bf16x8 qh0 = *(const bf16x8*)&Qhi[swz(w * 32 + cl, kb)];
      bf16x8 qh1 = *(const bf16x8*)&Qhi[swz(w * 32 + 16 + cl, kb)];
      bf16x8 ql0 = *(const bf16x8*)&Qlo[swz(w * 32 + cl, kb)];
      bf16x8 ql1 = *(const bf16x8*)&Qlo[swz(w * 32 + 16 + cl, kb)];
      #pragma unroll
      for (int n = 0; n < 8; ++n) {
        int o = swz(n * 16 + cl, kb);
        bf16x8 kh = *(const bf16x8*)&Khi[o];
        bf16x8 kl = *(const bf16x8*)&Klo[o];
        S[0][n] = MFMA16(qh0, kh, S[0][n]);
        S[1][n] = MFMA16(qh1, kh, S[1][n]);
        S[0][n] = MFMA16(qh0, kl, S[0][n]);
        S[1][n] = MFMA16(qh1, kl, S[1][n]);
        S[0][n] = MFMA16(ql0, kh, S[0][n]);
        S[1][n] = MFMA16(ql1, kh, S[1][n]);
      }
    }
  }

  // ---- softmax ----
  float inv_[2][4];
  float* lse = (float*)((char*)ws + WS_LSE_B);
  #pragma unroll
  for (int m = 0; m < 2; ++m)
    #pragma unroll
    for (int r = 0; r < 4; ++r) {
      float mx = S[m][0][r];
      #pragma unroll
      for (int n = 1; n < 8; ++n) mx = fmaxf(mx, S[m][n][r]);
      mx = fmaxf(mx, __shfl_xor(mx, 1));
      mx = fmaxf(mx, __shfl_xor(mx, 2));
      mx = fmaxf(mx, __shfl_xor(mx, 4));
      mx = fmaxf(mx, __shfl_xor(mx, 8));
      float sum = 0.f;
      #pragma unroll
      for (int n = 0; n < 8; ++n) { float e = __expf(S[m][n][r] - mx); S[m][n][r] = e; sum += e; }
      sum += __shfl_xor(sum, 1);
      sum += __shfl_xor(sum, 2);
      sum += __shfl_xor(sum, 4);
      sum += __shfl_xor(sum, 8);
      inv_[m][r] = 1.0f / sum;
      if (cl == 0) {
        int q = w * 32 + m * 16 + ag * 4 + r;
        lse[(((size_t)h * BATCH + b) << 13) + (qkp[q] & 8191)] = mx + __logf(sum);
      }
    }

  // ---- PV in two k-halves ----
  f32x4 O[4][2];
  #pragma unroll
  for (int mt = 0; mt < 4; ++mt)
    #pragma unroll
    for (int nt = 0; nt < 2; ++nt) O[mt][nt] = (f32x4){0.f, 0.f, 0.f, 0.f};

  #pragma unroll
  for (int half = 0; half < 2; ++half) {
    __syncthreads();
    // normalized P-half (hi/lo) into [0,32K), cvt_pk pairs over n4
    #pragma unroll
    for (int m = 0; m < 2; ++m)
      #pragma unroll
      for (int r = 0; r < 4; ++r) {
        int row = w * 32 + m * 16 + ag * 4 + r;
        int sw2 = (row & 7) << 4;
        float iv = inv_[m][r];
        float p0 = S[m][half * 4 + 0][r] * iv;
        float p1 = S[m][half * 4 + 1][r] * iv;
        float p2 = S[m][half * 4 + 2][r] * iv;
        float p3 = S[m][half * 4 + 3][r] * iv;
        u32 h01 = cvtpk(p0, p1), h23 = cvtpk(p2, p3);
        u32 e01 = cvtpk(p0 - uaf(h01 << 16), p1 - uaf(h01 & 0xFFFF0000u));
        u32 e23 = cvtpk(p2 - uaf(h23 << 16), p3 - uaf(h23 & 0xFFFF0000u));
        int base = row * 128;
        int o0 = base + ((2 * (0 * 16 + cl)) ^ sw2);
        int o1 = base + ((2 * (1 * 16 + cl)) ^ sw2);
        int o2 = base + ((2 * (2 * 16 + cl)) ^ sw2);
        int o3 = base + ((2 * (3 * 16 + cl)) ^ sw2);
        *(ushort*)&sm[o0] = (ushort)h01;         *(ushort*)&sm[16384 + o0] = (ushort)e01;
        *(ushort*)&sm[o1] = (ushort)(h01 >> 16); *(ushort*)&sm[16384 + o1] = (ushort)(e01 >> 16);
        *(ushort*)&sm[o2] = (ushort)h23;         *(ushort*)&sm[16384 + o2] = (ushort)e23;
        *(ushort*)&sm[o3] = (ushort)(h23 >> 16); *(ushort*)&sm[16384 + o3] = (ushort)(e23 >> 16);
      }
    if (half == 0) {   // stage V^T hi/lo into [32K,64K)
      int tok = t >> 1, dh = (t & 1) * 32;
      const float* vs = Vb + (size_t)(kkp[tok] & 8191) * DIM + dh;
      #pragma unroll
      for (int c4 = 0; c4 < 8; ++c4) {
        float4 a = *(const float4*)(vs + c4 * 4);
        u32 h01 = cvtpk(a.x, a.y), h23 = cvtpk(a.z, a.w);
        u32 e01 = cvtpk(a.x - uaf(h01 << 16), a.y - uaf(h01 & 0xFFFF0000u));
        u32 e23 = cvtpk(a.z - uaf(h23 << 16), a.w - uaf(h23 & 0xFFFF0000u));
        u32 hhv[4] = {h01 & 0xFFFFu, h01 >> 16, h23 & 0xFFFFu, h23 >> 16};
        u32 llv[4] = {e01 & 0xFFFFu, e01 >> 16, e23 & 0xFFFFu, e23 >> 16};
        #pragma unroll
        for (int j = 0; j < 4; ++j) {
          int dv = dh + c4 * 4 + j;
          int off = dv * 256 + ((2 * tok) ^ ((dv & 7) << 5));
          *(ushort*)&sm[32768 + off] = (ushort)hhv[j];
          *(ushort*)&sm[49152 + off] = (ushort)llv[j];
        }
      }
    }
    __syncthreads();
    #pragma unroll
    for (int k2 = 0; k2 < 2; ++k2) {
      int kbP = k2 * 64 + ag * 16;
      int kbV = half * 128 + k2 * 64 + ag * 16;
      bf16x8 p0h = *(const bf16x8*)&sm[swz(w * 32 + cl, kbP)];
      bf16x8 p0l = *(const bf16x8*)&sm[16384 + swz(w * 32 + cl, kbP)];
      bf16x8 p1h = *(const bf16x8*)&sm[swz(w * 32 + 16 + cl, kbP)];
      bf16x8 p1l = *(const bf16x8*)&sm[16384 + swz(w * 32 + 16 + cl, kbP)];
      #pragma unroll
      for (int mt = 0; mt < 4; ++mt) {
        int dv = mt * 16 + cl;
        int off = dv * 256 + (kbV ^ ((dv & 7) << 5));
        bf16x8 vh = *(const bf16x8*)&sm[32768 + off];
        bf16x8 vl = *(const bf16x8*)&sm[49152 + off];
        O[mt][0] = MFMA16(vh, p0h, O[mt][0]);
        O[mt][0] = MFMA16(vh, p0l, O[mt][0]);
        O[mt][0] = MFMA16(vl, p0h, O[mt][0]);
        O[mt][1] = MFMA16(vh, p1h, O[mt][1]);
        O[mt][1] = MFMA16(vh, p1l, O[mt][1]);
        O[mt][1] = MFMA16(vl, p1h, O[mt][1]);
      }
    }
  }

  // ---- epilogue: bf16 bo (R6) ----
  ushort* bo = (ushort*)((char*)ws + WS_BO_B);
  #pragma unroll
  for (int nt = 0; nt < 2; ++nt) {
    int q = w * 32 + nt * 16 + cl;
    int tok = (int)(qkp[q] & 8191);
    ushort* orow = bo + ((((size_t)h * BATCH + b) << 13) + tok) * 64;
    #pragma unroll
    for (int mt = 0; mt < 4; ++mt) {
      uint2 d2;
      d2.x = cvtpk(O[mt][nt][0], O[mt][nt][1]);
      d2.y = cvtpk(O[mt][nt][2], O[mt][nt][3]);
      *(uint2*)&orow[mt * 16 + ag * 4] = d2;
    }
  }
}

// ---------------- k_combine (bf16 bo) ----------------
__global__ __launch_bounds__(256) void smyrf_combine(const float* __restrict__ ws,
                                                     float* __restrict__ out) {
  int tid = blockIdx.x * 256 + threadIdx.x;
  int f4i = tid & 15;
  int n = (tid >> 4) & 8191;
  int b = tid >> 17;
  const float* lse = (const float*)((const char*)ws + WS_LSE_B);
  const ushort* bo = (const ushort*)((const char*)ws + WS_BO_B);
  float l[8];
  #pragma unroll
  for (int hh = 0; hh < 8; ++hh) l[hh] = lse[(((size_t)hh * BATCH + b) << 13) + n];
  float m = l[0];
  #pragma unroll
  for (int hh = 1; hh < 8; ++hh) m = fmaxf(m, l[hh]);
  float w[8]; float sum = 0.0f;
  #pragma unroll
  for (int hh = 0; hh < 8; ++hh) { w[hh] = __expf(l[hh] - m); sum += w[hh]; }
  float inv = 1.0f / sum;
  float4 a; a.x = a.y = a.z = a.w = 0.0f;
  #pragma unroll
  for (int hh = 0; hh < 8; ++hh) {
    const ushort* p = bo + ((((size_t)hh * BATCH + b) << 13) + n) * 64 + f4i * 4;
    uint2 dd = *(const uint2*)p;
    float ww = w[hh] * inv;
    a.x = fmaf(ww, uaf(dd.x << 16), a.x);
    a.y = fmaf(ww, uaf(dd.x & 0xFFFF0000u), a.y);
    a.z = fmaf(ww, uaf(dd.y << 16), a.z);
    a.w = fmaf(ww, uaf(dd.y & 0xFFFF0000u), a.w);
  }
  ((float4*)out)[tid] = a;
}

// ---------------- launch ----------------
extern "C" void kernel_launch(void* const* d_in, const int* in_sizes, int n_in,
                              void* d_out, int out_size, void* d_ws, size_t ws_size,
                              hipStream_t stream) {
  const float* q = (const float*)d_in[0];
  const float* k = (const float*)d_in[1];
  const float* v = (const float*)d_in[2];
  float* out = (float*)d_out;
  float* ws = (float*)d_ws;

  smyrf_rng<<<1, 256, 0, stream>>>(ws);
  smyrf_norms<<<256, 256, 0, stream>>>(q, k, ws);
  smyrf_keys<<<256, 256, 0, stream>>>(q, k, ws);
  smyrf_sort<<<64, 1024, 0, stream>>>(ws);
  smyrf_attn_mfma<<<NH * BATCH * NCLU, 256, 0, stream>>>(q, k, v, ws);
  smyrf_combine<<<2048, 256, 0, stream>>>(ws, out);
}

// Round 12
// 173.677 us; speedup vs baseline: 6.4361x; 1.0626x over previous
//
#include <hip/hip_runtime.h>
#include <stdint.h>

typedef unsigned int u32;
typedef unsigned long long u64;

// ---------------- problem constants ----------------
#define BATCH 4
#define NSEQ  8192
#define DIM   64
#define NH    8
#define CSZ   128
#define NCLU  64

// ---------------- workspace layout ----------------
#define WS_ALPHA   0
#define WS_BETA    528
#define WS_MAXB    536
#define WS_QN      1024
#define WS_KEYS_B  266240
#define WS_LSE_B   2363392
#define WS_BO_B    3411968      // bf16 [8][4][8192][64] = 32 MiB
// total = 36,966,400 bytes

typedef short bf16x8 __attribute__((ext_vector_type(8)));
typedef float f32x4 __attribute__((ext_vector_type(4)));
#define MFMA16(a, b, c) __builtin_amdgcn_mfma_f32_16x16x32_bf16(a, b, c, 0, 0, 0)

// packed f32->bf16 RNE
__device__ __forceinline__ u32 cvtpk(float lo, float hi) {
  u32 d;
  asm("v_cvt_pk_bf16_f32 %0, %1, %2" : "=v"(d) : "v"(lo), "v"(hi));
  return d;
}
__device__ __forceinline__ float uaf(u32 x) { return __uint_as_float(x); }

// split 8 consecutive f32 -> bf16 hi frag + lo (residual) frag. Pairing (2i,2i+1).
__device__ __forceinline__ void split8(const float* p, bf16x8& hi, bf16x8& lo) {
  float4 a = *(const float4*)p;
  float4 b = *(const float4*)(p + 4);
  u32 h0 = cvtpk(a.x, a.y), h1 = cvtpk(a.z, a.w);
  u32 h2 = cvtpk(b.x, b.y), h3 = cvtpk(b.z, b.w);
  u32 l0 = cvtpk(a.x - uaf(h0 << 16), a.y - uaf(h0 & 0xFFFF0000u));
  u32 l1 = cvtpk(a.z - uaf(h1 << 16), a.w - uaf(h1 & 0xFFFF0000u));
  u32 l2 = cvtpk(b.x - uaf(h2 << 16), b.y - uaf(h2 & 0xFFFF0000u));
  u32 l3 = cvtpk(b.z - uaf(h3 << 16), b.w - uaf(h3 & 0xFFFF0000u));
  union { u32 u[4]; bf16x8 v; } H, L;
  H.u[0] = h0; H.u[1] = h1; H.u[2] = h2; H.u[3] = h3;
  L.u[0] = l0; L.u[1] = l1; L.u[2] = l2; L.u[3] = l3;
  hi = H.v; lo = L.v;
}

// ---------------- Threefry-2x32 (JAX) ----------------
__device__ __forceinline__ void tf2x32(u32 k0, u32 k1, u32 x0, u32 x1, u32& o0, u32& o1) {
  u32 ks2 = k0 ^ k1 ^ 0x1BD11BDAu;
  x0 += k0; x1 += k1;
#define TF_RND(r) { x0 += x1; x1 = (x1 << (r)) | (x1 >> (32 - (r))); x1 ^= x0; }
  TF_RND(13) TF_RND(15) TF_RND(26) TF_RND(6)
  x0 += k1; x1 += ks2 + 1u;
  TF_RND(17) TF_RND(29) TF_RND(16) TF_RND(24)
  x0 += ks2; x1 += k0 + 2u;
  TF_RND(13) TF_RND(15) TF_RND(26) TF_RND(6)
  x0 += k0; x1 += k1 + 3u;
  TF_RND(17) TF_RND(29) TF_RND(16) TF_RND(24)
  x0 += k1; x1 += ks2 + 4u;
  TF_RND(13) TF_RND(15) TF_RND(26) TF_RND(6)
  x0 += ks2; x1 += k0 + 5u;
#undef TF_RND
  o0 = x0; o1 = x1;
}

__device__ __forceinline__ float bits01(u32 b) {
  return __uint_as_float((b >> 9) | 0x3f800000u) - 1.0f;
}

__device__ __forceinline__ float xla_erfinv(float x) {
  float x2 = __fmul_rn(x, x);
  float w = (float)(-log1p(-(double)x2));
  float p;
  if (w < 5.0f) {
    float ww = __fsub_rn(w, 2.5f);
    p = 2.81022636e-08f;
    p = __fadd_rn(3.43273939e-07f, __fmul_rn(p, ww));
    p = __fadd_rn(-3.5233877e-06f, __fmul_rn(p, ww));
    p = __fadd_rn(-4.39150654e-06f, __fmul_rn(p, ww));
    p = __fadd_rn(0.00021858087f, __fmul_rn(p, ww));
    p = __fadd_rn(-0.00125372503f, __fmul_rn(p, ww));
    p = __fadd_rn(-0.00417768164f, __fmul_rn(p, ww));
    p = __fadd_rn(0.246640727f, __fmul_rn(p, ww));
    p = __fadd_rn(1.50140941f, __fmul_rn(p, ww));
  } else {
    float ww = __fsub_rn(__fsqrt_rn(w), 3.0f);
    p = -0.000200214257f;
    p = __fadd_rn(0.000100950558f, __fmul_rn(p, ww));
    p = __fadd_rn(0.00134934322f, __fmul_rn(p, ww));
    p = __fadd_rn(-0.00367342844f, __fmul_rn(p, ww));
    p = __fadd_rn(0.00573950773f, __fmul_rn(p, ww));
    p = __fadd_rn(-0.0076224613f, __fmul_rn(p, ww));
    p = __fadd_rn(0.00943887047f, __fmul_rn(p, ww));
    p = __fadd_rn(1.00167406f, __fmul_rn(p, ww));
    p = __fadd_rn(2.83297682f, __fmul_rn(p, ww));
  }
  return __fmul_rn(p, x);
}

// ---------------- k_rng ----------------
__global__ __launch_bounds__(256) void smyrf_rng(float* ws) {
  int t = threadIdx.x;
  float* alpha = ws + WS_ALPHA;
  float* beta  = ws + WS_BETA;
  u32*   maxb  = (u32*)(ws + WS_MAXB);
  if (t < 8) maxb[t] = 0u;
  u32 ka0, ka1, kb0, kb1;
  tf2x32(0u, 42u, 0u, 0u, ka0, ka1);
  tf2x32(0u, 42u, 0u, 1u, kb0, kb1);
  const float LO = __uint_as_float(0xBF7FFFFFu);
  const float SQ2 = 1.4142135623730951f;
  for (int i = t; i < 528; i += 256) {
    u32 o0, o1; tf2x32(ka0, ka1, 0u, (u32)i, o0, o1);
    u32 bits = o0 ^ o1;
    float u = __fadd_rn(__fmul_rn(bits01(bits), 2.0f), LO);
    alpha[i] = __fmul_rn(SQ2, xla_erfinv(u));
  }
  if (t < 8) {
    u32 o0, o1; tf2x32(kb0, kb1, 0u, (u32)t, o0, o1);
    beta[t] = bits01(o0 ^ o1);
  }
}

// ---------------- k_norms ----------------
__global__ __launch_bounds__(256) void smyrf_norms(const float* __restrict__ Q,
                                                   const float* __restrict__ Kk,
                                                   float* ws) {
  int tid = blockIdx.x * 256 + threadIdx.x;
  int tensor = tid >> 15;
  const float* x = (tensor ? Kk : Q) + (size_t)(tid & 32767) * DIM;
  const float4* x4 = (const float4*)x;
  double s = 0.0;
  #pragma unroll
  for (int i = 0; i < 16; ++i) {
    float4 v = x4[i];
    s += (double)v.x * v.x + (double)v.y * v.y + (double)v.z * v.z + (double)v.w * v.w;
  }
  float qn = (float)sqrt(s);
  (ws + WS_QN)[tid] = qn;
  float wmax = qn;
  #pragma unroll
  for (int off = 1; off < 64; off <<= 1) wmax = fmaxf(wmax, __shfl_xor(wmax, off));
  __shared__ float red[4];
  int wave = threadIdx.x >> 6;
  if ((threadIdx.x & 63) == 0) red[wave] = wmax;
  __syncthreads();
  if (threadIdx.x == 0) {
    float m = fmaxf(fmaxf(red[0], red[1]), fmaxf(red[2], red[3]));
    int b = (tid >> 13) & 3;
    atomicMax((u32*)(ws + WS_MAXB) + tensor * 4 + b, __float_as_uint(m));
  }
}

// ---------------- k_keys ----------------
__global__ __launch_bounds__(256) void smyrf_keys(const float* __restrict__ Q,
                                                  const float* __restrict__ Kk,
                                                  float* ws) {
  int tid = blockIdx.x * 256 + threadIdx.x;
  int tensor = tid >> 15;
  int b = (tid >> 13) & 3;
  int n = tid & 8191;
  const float* x = (tensor ? Kk : Q) + (size_t)(tid & 32767) * DIM;
  float r[64];
  const float4* x4 = (const float4*)x;
  #pragma unroll
  for (int i = 0; i < 16; ++i) {
    float4 v = x4[i];
    r[4 * i] = v.x; r[4 * i + 1] = v.y; r[4 * i + 2] = v.z; r[4 * i + 3] = v.w;
  }
  const float* alpha = ws + WS_ALPHA;
  const float* beta  = ws + WS_BETA;
  const u32*   maxb  = (const u32*)(ws + WS_MAXB);
  float qn = (ws + WS_QN)[tid];
  float mq = __uint_as_float(maxb[b]);
  float mk = __uint_as_float(maxb[4 + b]);
  float M2 = __fadd_rn(__fmul_rn(mq, mq), __fmul_rn(mk, mk));
  float ex = __fsqrt_rn(fmaxf(__fsub_rn(M2, __fmul_rn(qn, qn)), 0.0f));
  u32* keys = (u32*)((char*)ws + WS_KEYS_B);
  #pragma unroll 1
  for (int hh = 0; hh < NH; ++hh) {
    const float* al = alpha + hh * 66;
    double dot = 0.0;
    #pragma unroll
    for (int d = 0; d < 64; ++d) dot = fma((double)r[d], (double)al[d], dot);
    dot = fma((double)ex, (double)al[64 + tensor], dot);
    float val = __fadd_rn((float)dot, beta[hh]);
    float fb = floorf(val);
    int ib = (fb >= 262143.f) ? 262143 : ((fb <= -262144.f) ? -262144 : (int)fb);
    keys[((size_t)tensor * NH * BATCH + (size_t)hh * BATCH + b) * NSEQ + n] =
        ((u32)(ib + 262144) << 13) | (u32)n;
  }
}

// ---------------- k_sort (R4): stable LDS radix, dynamic pass count ----------------
__global__ __launch_bounds__(1024) void smyrf_sort(float* ws) {
  __shared__ u32 arrA[8192];
  __shared__ u32 arrB[8192];
  __shared__ u32 hist[16][256];
  __shared__ u32 scanbuf[256];
  __shared__ u32 wmn[16], wmx[16], mnmx[2];
  u32* base = (u32*)((char*)ws + WS_KEYS_B) + (size_t)blockIdx.x * 8192;
  int t = threadIdx.x;
  int w = t >> 6, l = t & 63;
  u64 ltmask = (1ull << l) - 1ull;

  u32 mn = 0xFFFFFFFFu, mx = 0u;
  for (int i = t; i < 8192; i += 1024) {
    u32 k = base[i];
    arrA[i] = k;
    u32 bk = k >> 13;
    mn = min(mn, bk); mx = max(mx, bk);
  }
  #pragma unroll
  for (int off = 1; off < 64; off <<= 1) {
    mn = min(mn, (u32)__shfl_xor((int)mn, off));
    mx = max(mx, (u32)__shfl_xor((int)mx, off));
  }
  if (l == 0) { wmn[w] = mn; wmx[w] = mx; }
  __syncthreads();
  if (t == 0) {
    u32 a = wmn[0], bb = wmx[0];
    #pragma unroll
    for (int i = 1; i < 16; ++i) { a = min(a, wmn[i]); bb = max(bb, wmx[i]); }
    mnmx[0] = a; mnmx[1] = bb;
  }
  __syncthreads();
  u32 minb = mnmx[0];
  u32 range = mnmx[1] - minb;
  int npass = (range < 256u) ? 1 : ((range < 65536u) ? 2 : 3);

  u32* src = arrA;
  u32* dst = arrB;
  for (int p = 0; p < npass; ++p) {
    int sh = 8 * p;
    for (int i = t; i < 16 * 256; i += 1024) ((u32*)hist)[i] = 0u;
    __syncthreads();
    #pragma unroll 1
    for (int r = 0; r < 8; ++r) {
      u32 key = src[w * 512 + r * 64 + l];
      u32 d = (((key >> 13) - minb) >> sh) & 255u;
      atomicAdd(&hist[w][d], 1u);
    }
    __syncthreads();
    u32 mytot = 0;
    if (t < 256) {
      u32 run = 0;
      #pragma unroll
      for (int ww = 0; ww < 16; ++ww) { u32 c = hist[ww][t]; hist[ww][t] = run; run += c; }
      mytot = run;
      scanbuf[t] = run;
    }
    __syncthreads();
    for (int s = 1; s < 256; s <<= 1) {
      u32 v = 0;
      if (t < 256 && t >= s) v = scanbuf[t - s];
      __syncthreads();
      if (t < 256) scanbuf[t] += v;
      __syncthreads();
    }
    if (t < 256) {
      u32 off = scanbuf[t] - mytot;
      #pragma unroll
      for (int ww = 0; ww < 16; ++ww) hist[ww][t] += off;
    }
    __syncthreads();
    #pragma unroll 1
    for (int r = 0; r < 8; ++r) {
      u32 key = src[w * 512 + r * 64 + l];
      u32 d = (((key >> 13) - minb) >> sh) & 255u;
      u64 peers = ~0ull;
      #pragma unroll
      for (int bit = 0; bit < 8; ++bit) {
        bool myb = (d >> bit) & 1u;
        u64 vote = __ballot(myb);
        peers &= myb ? vote : ~vote;
      }
      u32 rank = (u32)__popcll(peers & ltmask);
      u32 cnt = (u32)__popcll(peers);
      int leaderLane = (int)__ffsll((long long)peers) - 1;
      u32 old = 0;
      if (l == leaderLane) old = atomicAdd(&hist[w][d], cnt);
      old = (u32)__shfl((int)old, leaderLane);
      dst[old + rank] = key;
    }
    __syncthreads();
    u32* tmp = src; src = dst; dst = tmp;
  }
  for (int i = t; i < 8192; i += 1024) base[i] = src[i];
}

// ---------------- k_attn (R8): 48KB LDS (3 blocks/CU), Q in regs, setprio ----------------
// LDS: K hi [0,16K) lo [16K,32K); after QK^T: P-half hi/lo same region;
//      VT-half hi [32K,40K) lo [40K,48K)  (64 dv rows x 128B)
__device__ __forceinline__ int swz(int row, int kb) { return row * 128 + (kb ^ ((row & 7) << 4)); }

__global__ __launch_bounds__(256, 3) void smyrf_attn_mfma(const float* __restrict__ Q,
                                                          const float* __restrict__ K,
                                                          const float* __restrict__ V,
                                                          float* __restrict__ ws) {
  __shared__ uint4 smem_u4[3072];   // 48 KB
  char* sm = (char*)smem_u4;
  int id = blockIdx.x;
  int c = id & 63, b = (id >> 6) & 3, h = id >> 8;
  int t = threadIdx.x;
  int lane = t & 63, w = t >> 6;
  int cl = lane & 15, ag = lane >> 4;

  const u32* keys = (const u32*)((const char*)ws + WS_KEYS_B);
  const u32* qkp = keys + ((size_t)h * BATCH + b) * NSEQ + c * CSZ;
  const u32* kkp = keys + (size_t)NH * BATCH * NSEQ + ((size_t)h * BATCH + b) * NSEQ + c * CSZ;
  const float* Qb = Q + (size_t)b * NSEQ * DIM;
  const float* Kb = K + (size_t)b * NSEQ * DIM;
  const float* Vb = V + (size_t)b * NSEQ * DIM;

  // ---- Q fragments: global -> registers (hi/lo), wave-private rows ----
  bf16x8 qh[2][2], ql[2][2];   // [kk][m], m=0: row w*32+cl, m=1: +16
  {
    int tok0 = (int)(qkp[w * 32 + cl] & 8191);
    int tok1 = (int)(qkp[w * 32 + 16 + cl] & 8191);
    const float* s0 = Qb + (size_t)tok0 * DIM;
    const float* s1 = Qb + (size_t)tok1 * DIM;
    #pragma unroll
    for (int kk_ = 0; kk_ < 2; ++kk_) {
      int e = kk_ * 32 + ag * 8;
      split8(s0 + e, qh[kk_][0], ql[kk_][0]);
      split8(s1 + e, qh[kk_][1], ql[kk_][1]);
    }
  }

  // ---- stage K hi/lo into [0,32K): thread t -> row t>>1, elems (t&1)*32..+32 ----
  {
    int row = t >> 1;
    int eh = (t & 1) * 32;
    int tok = (int)(kkp[row] & 8191);
    const float* src = Kb + (size_t)tok * DIM + eh;
    int sw = (row & 7) << 4;
    #pragma unroll
    for (int g = 0; g < 4; ++g) {
      bf16x8 hi, lo;
      split8(src + g * 8, hi, lo);
      int off = row * 128 + (((eh + g * 8) * 2) ^ sw);
      *(bf16x8*)&sm[off] = hi;
      *(bf16x8*)&sm[16384 + off] = lo;
    }
  }
  __syncthreads();

  // ---- QK^T ----
  f32x4 S[2][8];
  #pragma unroll
  for (int m = 0; m < 2; ++m)
    #pragma unroll
    for (int n = 0; n < 8; ++n) S[m][n] = (f32x4){0.f, 0.f, 0.f, 0.f};
  {
    const char* Khi = sm, *Klo = sm + 16384;
    __builtin_amdgcn_s_setprio(1);
    #pragma unroll
    for (int kk_ = 0; kk_ < 2; ++kk_) {
      int kb = kk_ * 64 + ag * 16;
      #pragma unroll
      for (int n = 0; n < 8; ++n) {
        int o = swz(n * 16 + cl, kb);
        bf16x8 kh = *(const bf16x8*)&Khi[o];
        bf16x8 kl = *(const bf16x8*)&Klo[o];
        S[0][n] = MFMA16(qh[kk_][0], kh, S[0][n]);
        S[1][n] = MFMA16(qh[kk_][1], kh, S[1][n]);
        S[0][n] = MFMA16(qh[kk_][0], kl, S[0][n]);
        S[1][n] = MFMA16(qh[kk_][1], kl, S[1][n]);
        S[0][n] = MFMA16(ql[kk_][0], kh, S[0][n]);
        S[1][n] = MFMA16(ql[kk_][1], kh, S[1][n]);
      }
    }
    __builtin_amdgcn_s_setprio(0);
  }

  // ---- softmax ----
  float inv_[2][4];
  float* lse = (float*)((char*)ws + WS_LSE_B);
  #pragma unroll
  for (int m = 0; m < 2; ++m)
    #pragma unroll
    for (int r = 0; r < 4; ++r) {
      float mx = S[m][0][r];
      #pragma unroll
      for (int n = 1; n < 8; ++n) mx = fmaxf(mx, S[m][n][r]);
      mx = fmaxf(mx, __shfl_xor(mx, 1));
      mx = fmaxf(mx, __shfl_xor(mx, 2));
      mx = fmaxf(mx, __shfl_xor(mx, 4));
      mx = fmaxf(mx, __shfl_xor(mx, 8));
      float sum = 0.f;
      #pragma unroll
      for (int n = 0; n < 8; ++n) { float e = __expf(S[m][n][r] - mx); S[m][n][r] = e; sum += e; }
      sum += __shfl_xor(sum, 1);
      sum += __shfl_xor(sum, 2);
      sum += __shfl_xor(sum, 4);
      sum += __shfl_xor(sum, 8);
      inv_[m][r] = 1.0f / sum;
      if (cl == 0) {
        int q = w * 32 + m * 16 + ag * 4 + r;
        lse[(((size_t)h * BATCH + b) << 13) + (qkp[q] & 8191)] = mx + __logf(sum);
      }
    }

  // ---- PV in two k-halves: P-half overwrites K region; VT-half at [32K,48K) ----
  f32x4 O[4][2];
  #pragma unroll
  for (int mt = 0; mt < 4; ++mt)
    #pragma unroll
    for (int nt = 0; nt < 2; ++nt) O[mt][nt] = (f32x4){0.f, 0.f, 0.f, 0.f};

  #pragma unroll
  for (int half = 0; half < 2; ++half) {
    __syncthreads();   // K readers (h0) / prior P+VT readers (h1) done
    // write normalized P-half (hi/lo) into [0,32K)
    #pragma unroll
    for (int m = 0; m < 2; ++m)
      #pragma unroll
      for (int r = 0; r < 4; ++r) {
        int row = w * 32 + m * 16 + ag * 4 + r;
        int sw2 = (row & 7) << 4;
        float iv = inv_[m][r];
        float p0 = S[m][half * 4 + 0][r] * iv;
        float p1 = S[m][half * 4 + 1][r] * iv;
        float p2 = S[m][half * 4 + 2][r] * iv;
        float p3 = S[m][half * 4 + 3][r] * iv;
        u32 h01 = cvtpk(p0, p1), h23 = cvtpk(p2, p3);
        u32 e01 = cvtpk(p0 - uaf(h01 << 16), p1 - uaf(h01 & 0xFFFF0000u));
        u32 e23 = cvtpk(p2 - uaf(h23 << 16), p3 - uaf(h23 & 0xFFFF0000u));
        int base = row * 128;
        int o0 = base + ((2 * (0 * 16 + cl)) ^ sw2);
        int o1 = base + ((2 * (1 * 16 + cl)) ^ sw2);
        int o2 = base + ((2 * (2 * 16 + cl)) ^ sw2);
        int o3 = base + ((2 * (3 * 16 + cl)) ^ sw2);
        *(ushort*)&sm[o0] = (ushort)h01;         *(ushort*)&sm[16384 + o0] = (ushort)e01;
        *(ushort*)&sm[o1] = (ushort)(h01 >> 16); *(ushort*)&sm[16384 + o1] = (ushort)(e01 >> 16);
        *(ushort*)&sm[o2] = (ushort)h23;         *(ushort*)&sm[16384 + o2] = (ushort)e23;
        *(ushort*)&sm[o3] = (ushort)(h23 >> 16); *(ushort*)&sm[16384 + o3] = (ushort)(e23 >> 16);
      }
    // stage VT half (64 tokens x 64 dv), hi/lo at [32K,40K)/[40K,48K)
    {
      int tokL = t >> 2;
      int dh = (t & 3) * 16;
      int tok = (int)(kkp[half * 64 + tokL] & 8191);
      const float* vs = Vb + (size_t)tok * DIM + dh;
      #pragma unroll
      for (int g = 0; g < 4; ++g) {
        float4 a = *(const float4*)(vs + g * 4);
        u32 h01 = cvtpk(a.x, a.y), h23 = cvtpk(a.z, a.w);
        u32 e01 = cvtpk(a.x - uaf(h01 << 16), a.y - uaf(h01 & 0xFFFF0000u));
        u32 e23 = cvtpk(a.z - uaf(h23 << 16), a.w - uaf(h23 & 0xFFFF0000u));
        u32 hv[4] = {h01 & 0xFFFFu, h01 >> 16, h23 & 0xFFFFu, h23 >> 16};
        u32 lv[4] = {e01 & 0xFFFFu, e01 >> 16, e23 & 0xFFFFu, e23 >> 16};
        #pragma unroll
        for (int j = 0; j < 4; ++j) {
          int dv = dh + g * 4 + j;
          int off = dv * 128 + ((2 * tokL) ^ ((dv & 7) << 4));
          *(ushort*)&sm[32768 + off] = (ushort)hv[j];
          *(ushort*)&sm[40960 + off] = (ushort)lv[j];
        }
      }
    }
    __syncthreads();
    __builtin_amdgcn_s_setprio(1);
    #pragma unroll
    for (int k2 = 0; k2 < 2; ++k2) {
      int kb = k2 * 64 + ag * 16;   // within 128B row (both P-half and VT-half)
      bf16x8 p0h = *(const bf16x8*)&sm[swz(w * 32 + cl, kb)];
      bf16x8 p0l = *(const bf16x8*)&sm[16384 + swz(w * 32 + cl, kb)];
      bf16x8 p1h = *(const bf16x8*)&sm[swz(w * 32 + 16 + cl, kb)];
      bf16x8 p1l = *(const bf16x8*)&sm[16384 + swz(w * 32 + 16 + cl, kb)];
      #pragma unroll
      for (int mt = 0; mt < 4; ++mt) {
        int dv = mt * 16 + cl;
        int off = dv * 128 + (kb ^ ((dv & 7) << 4));
        bf16x8 vh = *(const bf16x8*)&sm[32768 + off];
        bf16x8 vl = *(const bf16x8*)&sm[40960 + off];
        O[mt][0] = MFMA16(vh, p0h, O[mt][0]);
        O[mt][0] = MFMA16(vh, p0l, O[mt][0]);
        O[mt][0] = MFMA16(vl, p0h, O[mt][0]);
        O[mt][1] = MFMA16(vh, p1h, O[mt][1]);
        O[mt][1] = MFMA16(vh, p1l, O[mt][1]);
        O[mt][1] = MFMA16(vl, p1h, O[mt][1]);
      }
    }
    __builtin_amdgcn_s_setprio(0);
  }

  // ---- epilogue: bf16 bo ----
  ushort* bo = (ushort*)((char*)ws + WS_BO_B);
  #pragma unroll
  for (int nt = 0; nt < 2; ++nt) {
    int q = w * 32 + nt * 16 + cl;
    int tok = (int)(qkp[q] & 8191);
    ushort* orow = bo + ((((size_t)h * BATCH + b) << 13) + tok) * 64;
    #pragma unroll
    for (int mt = 0; mt < 4; ++mt) {
      uint2 d2;
      d2.x = cvtpk(O[mt][nt][0], O[mt][nt][1]);
      d2.y = cvtpk(O[mt][nt][2], O[mt][nt][3]);
      *(uint2*)&orow[mt * 16 + ag * 4] = d2;
    }
  }
}

// ---------------- k_combine (bf16 bo) ----------------
__global__ __launch_bounds__(256) void smyrf_combine(const float* __restrict__ ws,
                                                     float* __restrict__ out) {
  int tid = blockIdx.x * 256 + threadIdx.x;
  int f4i = tid & 15;
  int n = (tid >> 4) & 8191;
  int b = tid >> 17;
  const float* lse = (const float*)((const char*)ws + WS_LSE_B);
  const ushort* bo = (const ushort*)((const char*)ws + WS_BO_B);
  float l[8];
  #pragma unroll
  for (int hh = 0; hh < 8; ++hh) l[hh] = lse[(((size_t)hh * BATCH + b) << 13) + n];
  float m = l[0];
  #pragma unroll
  for (int hh = 1; hh < 8; ++hh) m = fmaxf(m, l[hh]);
  float w[8]; float sum = 0.0f;
  #pragma unroll
  for (int hh = 0; hh < 8; ++hh) { w[hh] = __expf(l[hh] - m); sum += w[hh]; }
  float inv = 1.0f / sum;
  float4 a; a.x = a.y = a.z = a.w = 0.0f;
  #pragma unroll
  for (int hh = 0; hh < 8; ++hh) {
    const ushort* p = bo + ((((size_t)hh * BATCH + b) << 13) + n) * 64 + f4i * 4;
    uint2 dd = *(const uint2*)p;
    float ww = w[hh] * inv;
    a.x = fmaf(ww, uaf(dd.x << 16), a.x);
    a.y = fmaf(ww, uaf(dd.x & 0xFFFF0000u), a.y);
    a.z = fmaf(ww, uaf(dd.y << 16), a.z);
    a.w = fmaf(ww, uaf(dd.y & 0xFFFF0000u), a.w);
  }
  ((float4*)out)[tid] = a;
}

// ---------------- launch ----------------
extern "C" void kernel_launch(void* const* d_in, const int* in_sizes, int n_in,
                              void* d_out, int out_size, void* d_ws, size_t ws_size,
                              hipStream_t stream) {
  const float* q = (const float*)d_in[0];
  const float* k = (const float*)d_in[1];
  const float* v = (const float*)d_in[2];
  float* out = (float*)d_out;
  float* ws = (float*)d_ws;

  smyrf_rng<<<1, 256, 0, stream>>>(ws);
  smyrf_norms<<<256, 256, 0, stream>>>(q, k, ws);
  smyrf_keys<<<256, 256, 0, stream>>>(q, k, ws);
  smyrf_sort<<<64, 1024, 0, stream>>>(ws);
  smyrf_attn_mfma<<<NH * BATCH * NCLU, 256, 0, stream>>>(q, k, v, ws);
  smyrf_combine<<<2048, 256, 0, stream>>>(ws, out);
}